// Round 12
// baseline (3574.583 us; speedup 1.0000x reference)
//
#include <hip/hip_runtime.h>
#include <hip/hip_bf16.h>
#include <math.h>

// TransformerDecoder2dLayer on MI355X (gfx950).
// Round 12: non-temporal epilogue stores + residual loads (streaming data was
// evicting A/W tiles from L2 — FF1 FETCH 270MB vs 175MB ideal). No other
// changes from round 11.

#define F_DIM 120
#define B_DIM 64
#define J_DIM 22
#define H_DIM 4
#define M_TOK (F_DIM * B_DIM * J_DIM) // 168960

#define DEV static __device__ __forceinline__

typedef short bf16x8 __attribute__((ext_vector_type(8)));
typedef short us8 __attribute__((ext_vector_type(8)));
typedef float f32x4 __attribute__((ext_vector_type(4)));

struct __align__(8) us4 { unsigned short x, y, z, w; };

DEV unsigned short f2b(float f) {
  unsigned u = __float_as_uint(f);
  u += 0x7fffu + ((u >> 16) & 1u);
  return (unsigned short)(u >> 16);
}
DEV float b2f(unsigned short u) { return __uint_as_float(((unsigned)u) << 16); }

#define GLOAD16(g, l)                                                          \
  __builtin_amdgcn_global_load_lds(                                            \
      (const __attribute__((address_space(1))) void*)(g),                      \
      (__attribute__((address_space(3))) void*)(l), 16, 0, 0)

enum { EPI_QKV = 0, EPI_GELU = 1, EPI_RES = 2, EPI_ACC = 3, EPI_RESB = 4,
       EPI_ROB = 5,   // f32 res  -> bf16 out (o0)
       EPI_RBB = 6 }; // bf16 res -> bf16 out (o0); res may alias o0 (elemwise)

// ---------------------------------------------------------------------------
__global__ __launch_bounds__(256)
void cast_k(const float* __restrict__ in, unsigned short* __restrict__ out, int n8) {
  for (int i = blockIdx.x * 256 + threadIdx.x; i < n8; i += gridDim.x * 256) {
    const float4 a = ((const float4*)in)[i * 2];
    const float4 b = ((const float4*)in)[i * 2 + 1];
    us8 v;
    v[0] = f2b(a.x); v[1] = f2b(a.y); v[2] = f2b(a.z); v[3] = f2b(a.w);
    v[4] = f2b(b.x); v[5] = f2b(b.y); v[6] = f2b(b.z); v[7] = f2b(b.w);
    __builtin_nontemporal_store(v, (us8*)&out[i * 8]);
  }
}

// ---------------------------------------------------------------------------
// Weight transpose + cast: W (K x N f32) -> WT (N x K bf16), generic (W1/W2).
__global__ __launch_bounds__(256)
void tcast_k(const float* __restrict__ W, unsigned short* __restrict__ WT, int K, int N) {
  __shared__ float t[32][33];
  const int n0 = blockIdx.x * 32, k0 = blockIdx.y * 32;
  const int tx = threadIdx.x, ty = threadIdx.y;
#pragma unroll
  for (int i = 0; i < 4; ++i)
    t[ty + i * 8][tx] = W[(size_t)(k0 + ty + i * 8) * N + n0 + tx];
  __syncthreads();
#pragma unroll
  for (int i = 0; i < 4; ++i)
    WT[(size_t)(n0 + ty + i * 8) * K + k0 + tx] = f2b(t[tx][ty + i * 8]);
}

// Batched 512x512 transpose+cast for the 8 attention weights (blockIdx.z).
struct Tc8Args { const float* W[8]; unsigned short* WT[8]; };
__global__ __launch_bounds__(256)
void tcast8_k(Tc8Args a) {
  __shared__ float t[32][33];
  const float* W = a.W[blockIdx.z];
  unsigned short* WT = a.WT[blockIdx.z];
  const int n0 = blockIdx.x * 32, k0 = blockIdx.y * 32;
  const int tx = threadIdx.x, ty = threadIdx.y;
#pragma unroll
  for (int i = 0; i < 4; ++i)
    t[ty + i * 8][tx] = W[(size_t)(k0 + ty + i * 8) * 512 + n0 + tx];
  __syncthreads();
#pragma unroll
  for (int i = 0; i < 4; ++i)
    WT[(size_t)(n0 + ty + i * 8) * 512 + k0 + tx] = f2b(t[tx][ty + i * 8]);
}

// ---------------------------------------------------------------------------
// ts-token K/V projections, all 4 in one launch.
struct TsArgs { const float* W[4]; const float* bias[4]; unsigned short* out[4]; };
__global__ __launch_bounds__(1024)
void tsproj_k(const float* __restrict__ ts, TsArgs a) {
  __shared__ float tsr[512];
  __shared__ float red[3][256];
  const int b = blockIdx.x;
  const int nb = blockIdx.y;
  const int pj = blockIdx.z;
  const int t = threadIdx.x;
  const int n = nb * 256 + (t & 255);
  const int kh = t >> 8;
  if (t < 512) tsr[t] = ts[b * 512 + t];
  __syncthreads();
  const float* W = a.W[pj];
  float acc = 0.f;
  const int k0 = kh * 128;
  for (int k = k0; k < k0 + 128; ++k)
    acc += tsr[k] * W[(size_t)k * 512 + n];
  if (kh) red[kh - 1][t & 255] = acc;
  __syncthreads();
  if (kh == 0) {
    acc += red[0][t & 255] + red[1][t & 255] + red[2][t & 255];
    a.out[pj][b * 512 + n] = f2b(acc + a.bias[pj][n]);
  }
}

// ---------------------------------------------------------------------------
template<int EPI>
DEV void epi_store(float v, int row, int col, const float* b0, const float* b1,
                   const float* b2, const void* res, float* outF,
                   unsigned short* o0, unsigned short* o1, unsigned short* o2,
                   int ldo, float scale) {
  if constexpr (EPI == EPI_QKV) {
    const int seg = col >> 9;
    const int cl = col & 511;
    const float* bs = (seg == 0) ? b0 : (seg == 1) ? b1 : b2;
    unsigned short* ob = (seg == 0) ? o0 : (seg == 1) ? o1 : o2;
    const float sc = (seg == 0) ? scale : 1.f;
    v = (v + bs[cl]) * sc;
    __builtin_nontemporal_store(f2b(v), &ob[(size_t)row * 512 + cl]);
  } else if constexpr (EPI == EPI_GELU) {
    v += b0[col];
    const float a2 = 1.5957691216057308f * (v + 0.044715f * v * v * v);
    const float g = v / (1.f + __expf(-a2));
    __builtin_nontemporal_store(f2b(g), &o0[(size_t)row * ldo + col]);
  } else if constexpr (EPI == EPI_RES) {
    const size_t off = (size_t)row * 512 + col;
    const float r = __builtin_nontemporal_load(&((const float*)res)[off]);
    __builtin_nontemporal_store(v + b0[col] + r, &outF[off]);
  } else if constexpr (EPI == EPI_RESB) {
    const size_t off = (size_t)row * 512 + col;
    const unsigned short r = __builtin_nontemporal_load(&((const unsigned short*)res)[off]);
    __builtin_nontemporal_store(v + b0[col] + b2f(r), &outF[off]);
  } else if constexpr (EPI == EPI_ROB) {
    const size_t off = (size_t)row * 512 + col;
    const float r = __builtin_nontemporal_load(&((const float*)res)[off]);
    __builtin_nontemporal_store(f2b(v + b0[col] + r), &o0[off]);
  } else if constexpr (EPI == EPI_RBB) {
    const size_t off = (size_t)row * 512 + col;
    const unsigned short r = __builtin_nontemporal_load(&((const unsigned short*)res)[off]);
    __builtin_nontemporal_store(f2b(v + b0[col] + b2f(r)), &o0[off]);
  } else { // EPI_ACC
    const size_t off = (size_t)row * 512 + col;
    outF[off] = v + outF[off];
  }
}

// ---------------------------------------------------------------------------
// 256x128 GEMM: C(M x nx*128) = A(M x nk) @ W(nk x N); A bf16, W as WT bf16.
// BK=32, 8 waves (4m x 2n) of 64x64. global_load_lds 16B into triple-buffered
// linear LDS; stage t+2 at step t; counted vmcnt(3) + one s_barrier per step.
template<int EPI>
__global__ __launch_bounds__(512, 4)
void gemm256_k(const unsigned short* __restrict__ Ab, const unsigned short* __restrict__ Wt,
               const float* __restrict__ b0, const float* __restrict__ b1, const float* __restrict__ b2,
               const void* __restrict__ res, float* __restrict__ outF,
               unsigned short* __restrict__ o0, unsigned short* __restrict__ o1, unsigned short* __restrict__ o2,
               int lda, int ldw, int ldo, int nk, int nx, float scale) {
  __shared__ unsigned short As[3][8192];   // 256 x 32
  __shared__ unsigned short Bs[3][4096];   // 128 x 32
  const int tid = threadIdx.x;
  const int chunkg = gridDim.x >> 3;       // XCD-chunked bijective swizzle (nwg%8==0)
  const int wg = (blockIdx.x & 7) * chunkg + (blockIdx.x >> 3);
  const int nbase = (wg % nx) * 128;
  const int mbase = (wg / nx) * 256;
  const int lane = tid & 63;
  const int w = tid >> 6;
  const int wr = (w >> 1) * 64;
  const int wc = (w & 1) * 64;
  const int l15 = lane & 15;
  const int lhi = lane >> 4;

  const int crow = lane >> 2;
  const int ccol = (((lane & 3) ^ ((lane >> 3) & 3)) << 3);
  const unsigned short* gA0 = Ab + (size_t)(mbase + 32 * w + crow) * lda + ccol;
  const unsigned short* gA1 = gA0 + (size_t)16 * lda;
  const unsigned short* gB0 = Wt + (size_t)(nbase + 16 * w + crow) * ldw + ccol;

  auto stage = [&](int bb, int kt) {   // 3 vmem ops / wave
    GLOAD16(gA0 + kt, &As[bb][(2 * w) * 512]);
    GLOAD16(gA1 + kt, &As[bb][(2 * w + 1) * 512]);
    GLOAD16(gB0 + kt, &Bs[bb][w * 512]);
  };

  f32x4 acc[4][4] = {};
  const int KT = nk >> 5;
  const int swz = ((lhi ^ ((l15 >> 1) & 3)) << 3);

  stage(0, 0);
  stage(1, 32);
  asm volatile("s_waitcnt vmcnt(3)" ::: "memory");
  __builtin_amdgcn_s_barrier();

  for (int t = 0; t < KT; ++t) {
    const unsigned short* as = As[t % 3];
    const unsigned short* bs = Bs[t % 3];
    if (t + 2 < KT) stage((t + 2) % 3, (t + 2) << 5);
    bf16x8 afr[4], bfr[4];
#pragma unroll
    for (int i = 0; i < 4; ++i) afr[i] = *(const bf16x8*)&as[(wr + i * 16 + l15) * 32 + swz];
#pragma unroll
    for (int j = 0; j < 4; ++j) bfr[j] = *(const bf16x8*)&bs[(wc + j * 16 + l15) * 32 + swz];
#pragma unroll
    for (int i = 0; i < 4; ++i)
#pragma unroll
      for (int j = 0; j < 4; ++j)
        acc[i][j] = __builtin_amdgcn_mfma_f32_16x16x32_bf16(afr[i], bfr[j], acc[i][j], 0, 0, 0);
    if (t + 2 < KT)      asm volatile("s_waitcnt vmcnt(3) lgkmcnt(0)" ::: "memory");
    else if (t + 1 < KT) asm volatile("s_waitcnt vmcnt(0) lgkmcnt(0)" ::: "memory");
    else                 asm volatile("s_waitcnt lgkmcnt(0)" ::: "memory");
    __builtin_amdgcn_s_barrier();
  }

#pragma unroll
  for (int i = 0; i < 4; ++i)
#pragma unroll
    for (int j = 0; j < 4; ++j) {
      const int row0 = mbase + wr + i * 16 + (lhi << 2);
      const int col = nbase + wc + j * 16 + l15;
#pragma unroll
      for (int q = 0; q < 4; ++q)
        epi_store<EPI>(acc[i][j][q], row0 + q, col, b0, b1, b2, res, outF, o0, o1, o2, ldo, scale);
    }
}

// ---------------------------------------------------------------------------
// 128x128 pipelined GEMM — small-ws fallback path.
template<int EPI>
__global__ __launch_bounds__(256)
void gemm_k(const unsigned short* __restrict__ Ab, const unsigned short* __restrict__ Wt,
            const float* __restrict__ b0, const float* __restrict__ b1, const float* __restrict__ b2,
            const void* __restrict__ res, float* __restrict__ outF,
            unsigned short* __restrict__ o0, unsigned short* __restrict__ o1, unsigned short* __restrict__ o2,
            int lda, int ldw, int ldo, int nk, int nx, float scale) {
  __shared__ unsigned short As[3][4096];
  __shared__ unsigned short Bs[3][4096];
  const int tid = threadIdx.x;
  const int chunkg = gridDim.x >> 3;
  const int wg = (blockIdx.x & 7) * chunkg + (blockIdx.x >> 3);
  const int nbase = (wg % nx) * 128;
  const int mbase = (wg / nx) * 128;
  const int lane = tid & 63;
  const int w = tid >> 6;
  const int wr = (w >> 1) * 64;
  const int wc = (w & 1) * 64;
  const int l15 = lane & 15;
  const int lhi = lane >> 4;

  const int crow = lane >> 2;
  const int ccol = (((lane & 3) ^ ((lane >> 3) & 3)) << 3);
  const unsigned short* gA0 = Ab + (size_t)(mbase + 32 * w + crow) * lda + ccol;
  const unsigned short* gA1 = gA0 + (size_t)16 * lda;
  const unsigned short* gB0 = Wt + (size_t)(nbase + 32 * w + crow) * ldw + ccol;
  const unsigned short* gB1 = gB0 + (size_t)16 * ldw;

  auto stage = [&](int bb, int kt) {
    GLOAD16(gA0 + kt, &As[bb][(2 * w) * 512]);
    GLOAD16(gA1 + kt, &As[bb][(2 * w + 1) * 512]);
    GLOAD16(gB0 + kt, &Bs[bb][(2 * w) * 512]);
    GLOAD16(gB1 + kt, &Bs[bb][(2 * w + 1) * 512]);
  };

  f32x4 acc[4][4] = {};
  const int KT = nk >> 5;
  const int swz = ((lhi ^ ((l15 >> 1) & 3)) << 3);

  stage(0, 0);
  stage(1, 32);
  asm volatile("s_waitcnt vmcnt(4)" ::: "memory");
  __builtin_amdgcn_s_barrier();

  for (int t = 0; t < KT; ++t) {
    const unsigned short* as = As[t % 3];
    const unsigned short* bs = Bs[t % 3];
    if (t + 2 < KT) stage((t + 2) % 3, (t + 2) << 5);
    bf16x8 afr[4], bfr[4];
#pragma unroll
    for (int i = 0; i < 4; ++i) afr[i] = *(const bf16x8*)&as[(wr + i * 16 + l15) * 32 + swz];
#pragma unroll
    for (int j = 0; j < 4; ++j) bfr[j] = *(const bf16x8*)&bs[(wc + j * 16 + l15) * 32 + swz];
#pragma unroll
    for (int i = 0; i < 4; ++i)
#pragma unroll
      for (int j = 0; j < 4; ++j)
        acc[i][j] = __builtin_amdgcn_mfma_f32_16x16x32_bf16(afr[i], bfr[j], acc[i][j], 0, 0, 0);
    if (t + 2 < KT)      asm volatile("s_waitcnt vmcnt(4) lgkmcnt(0)" ::: "memory");
    else if (t + 1 < KT) asm volatile("s_waitcnt vmcnt(0) lgkmcnt(0)" ::: "memory");
    else                 asm volatile("s_waitcnt lgkmcnt(0)" ::: "memory");
    __builtin_amdgcn_s_barrier();
  }

#pragma unroll
  for (int i = 0; i < 4; ++i)
#pragma unroll
    for (int j = 0; j < 4; ++j) {
      const int row0 = mbase + wr + i * 16 + (lhi << 2);
      const int col = nbase + wc + j * 16 + l15;
#pragma unroll
      for (int q = 0; q < 4; ++q)
        epi_store<EPI>(acc[i][j][q], row0 + q, col, b0, b1, b2, res, outF, o0, o1, o2, ldo, scale);
    }
}

// ---------------------------------------------------------------------------
// Legacy reg-staging GEMM for f32 A (small-ws fallback only).
template<int EPI>
__global__ __launch_bounds__(256)
void gemmf_k(const float* __restrict__ Af, const unsigned short* __restrict__ Wt,
             const float* __restrict__ b0, const float* __restrict__ b1, const float* __restrict__ b2,
             const void* __restrict__ res, float* __restrict__ outF,
             unsigned short* __restrict__ o0, unsigned short* __restrict__ o1, unsigned short* __restrict__ o2,
             int lda, int ldw, int ldo, int nk, int nx, float scale) {
  __shared__ unsigned short As[128][40];
  __shared__ unsigned short Bs[128][40];
  const int tid = threadIdx.x;
  const int chunkg = gridDim.x >> 3;
  const int wg = (blockIdx.x & 7) * chunkg + (blockIdx.x >> 3);
  const int nbase = (wg % nx) * 128;
  const int mbase = (wg / nx) * 128;
  const int lane = tid & 63;
  const int w = tid >> 6;
  const int wr = (w >> 1) * 64;
  const int wc = (w & 1) * 64;
  const int l15 = lane & 15;
  const int lhi = lane >> 4;

  float4 ra[4];
  us4 rb[4];
  auto loadAB = [&](int kt) {
#pragma unroll
    for (int i = 0; i < 4; ++i) {
      const int g = i * 256 + tid;
      const int r = g >> 3;
      const int c = (g & 7) << 2;
      ra[i] = *(const float4*)(Af + (size_t)(mbase + r) * lda + kt + c);
      rb[i] = *(const us4*)(Wt + (size_t)(nbase + r) * ldw + kt + c);
    }
  };
  auto storeAB = [&]() {
#pragma unroll
    for (int i = 0; i < 4; ++i) {
      const int g = i * 256 + tid;
      const int r = g >> 3;
      const int c = (g & 7) << 2;
      us4 ua;
      ua.x = f2b(ra[i].x); ua.y = f2b(ra[i].y); ua.z = f2b(ra[i].z); ua.w = f2b(ra[i].w);
      *(us4*)&As[r][c] = ua;
      *(us4*)&Bs[r][c] = rb[i];
    }
  };

  f32x4 acc[4][4] = {};
  const int KT = nk >> 5;
  loadAB(0);
  storeAB();
  __syncthreads();
  for (int t = 0; t < KT; ++t) {
    if (t + 1 < KT) loadAB((t + 1) << 5);
    bf16x8 afr[4], bfr[4];
    const int klo = lhi << 3;
#pragma unroll
    for (int i = 0; i < 4; ++i) afr[i] = *(const bf16x8*)&As[wr + i * 16 + l15][klo];
#pragma unroll
    for (int j = 0; j < 4; ++j) bfr[j] = *(const bf16x8*)&Bs[wc + j * 16 + l15][klo];
#pragma unroll
    for (int i = 0; i < 4; ++i)
#pragma unroll
      for (int j = 0; j < 4; ++j)
        acc[i][j] = __builtin_amdgcn_mfma_f32_16x16x32_bf16(afr[i], bfr[j], acc[i][j], 0, 0, 0);
    __syncthreads();
    if (t + 1 < KT) { storeAB(); __syncthreads(); }
  }

#pragma unroll
  for (int i = 0; i < 4; ++i)
#pragma unroll
    for (int j = 0; j < 4; ++j) {
      const int row0 = mbase + wr + i * 16 + (lhi << 2);
      const int col = nbase + wc + j * 16 + l15;
#pragma unroll
      for (int q = 0; q < 4; ++q)
        epi_store<EPI>(acc[i][j][q], row0 + q, col, b0, b1, b2, res, outF, o0, o1, o2, ldo, scale);
    }
}

// ---------------------------------------------------------------------------
// Temporal MFMA attention. Block = (instance, head): 1408*4 blocks, 4 waves.
__global__ __launch_bounds__(256)
void attn_t_k(const unsigned short* __restrict__ Qb, const unsigned short* __restrict__ Kb,
              const unsigned short* __restrict__ Vb, const unsigned short* __restrict__ kts,
              const unsigned short* __restrict__ vts, unsigned short* __restrict__ Ob) {
  __shared__ unsigned short Ps[128][134];
  __shared__ unsigned short Vt[64][134];
  const int tid = threadIdx.x;
  const int inst = blockIdx.x >> 2;
  const int h = blockIdx.x & 3;
  const int b = inst & (B_DIM - 1);
  const size_t rowbase = (size_t)inst * 120;
  const int hoff = h * 128;
  const int lane = tid & 63;
  const int w = tid >> 6;
  const int wr = w * 32;
  const int l15 = lane & 15;
  const int lhi = lane >> 4;

  auto stageV = [&](int half) {
    for (int e = tid; e < 2048; e += 256) {
      const int d4 = (e & 15) << 2;
      const int key = e >> 4;
      us4 v;
      if (key <= 120) {
        const unsigned short* src = (key == 0) ? (vts + b * 512) : (Vb + (rowbase + key - 1) * 512);
        v = *(const us4*)(src + hoff + half * 64 + d4);
      } else { v.x = 0; v.y = 0; v.z = 0; v.w = 0; }
      Vt[d4 + 0][key] = v.x; Vt[d4 + 1][key] = v.y; Vt[d4 + 2][key] = v.z; Vt[d4 + 3][key] = v.w;
    }
  };
  stageV(0);

  bf16x8 qa[2][4];
#pragma unroll
  for (int i = 0; i < 2; ++i) {
    const int row = min(wr + i * 16 + l15, 119);
    const unsigned short* qp = Qb + (rowbase + row) * 512 + hoff;
#pragma unroll
    for (int kt = 0; kt < 4; ++kt)
      qa[i][kt] = *(const bf16x8*)(qp + kt * 32 + lhi * 8);
  }

  f32x4 acc[2][8] = {};
#pragma unroll
  for (int kt = 0; kt < 4; ++kt) {
    const int klo = kt * 32 + lhi * 8;
    bf16x8 kb[8];
#pragma unroll
    for (int j = 0; j < 8; ++j) {
      const int key = min(j * 16 + l15, 120);
      const unsigned short* kp = (key == 0) ? (kts + b * 512) : (Kb + (rowbase + key - 1) * 512);
      kb[j] = *(const bf16x8*)(kp + hoff + klo);
    }
#pragma unroll
    for (int i = 0; i < 2; ++i)
#pragma unroll
      for (int j = 0; j < 8; ++j)
        acc[i][j] = __builtin_amdgcn_mfma_f32_16x16x32_bf16(qa[i][kt], kb[j], acc[i][j], 0, 0, 0);
  }

  float rinv[2][4];
#pragma unroll
  for (int i = 0; i < 2; ++i)
#pragma unroll
    for (int q = 0; q < 4; ++q) {
      float m = -1e30f;
#pragma unroll
      for (int j = 0; j < 8; ++j)
        if (j * 16 + l15 <= 120) m = fmaxf(m, acc[i][j][q]);
#pragma unroll
      for (int mk = 1; mk < 16; mk <<= 1) m = fmaxf(m, __shfl_xor(m, mk, 64));
      float s = 0.f;
#pragma unroll
      for (int j = 0; j < 8; ++j) {
        const float e = (j * 16 + l15 <= 120) ? __expf(acc[i][j][q] - m) : 0.f;
        acc[i][j][q] = e; s += e;
      }
#pragma unroll
      for (int mk = 1; mk < 16; mk <<= 1) s += __shfl_xor(s, mk, 64);
      rinv[i][q] = 1.f / s;
    }

#pragma unroll
  for (int i = 0; i < 2; ++i)
#pragma unroll
    for (int j = 0; j < 8; ++j)
#pragma unroll
      for (int q = 0; q < 4; ++q)
        Ps[wr + i * 16 + lhi * 4 + q][j * 16 + l15] = f2b(acc[i][j][q]);

  __syncthreads();

#pragma unroll
  for (int half = 0; half < 2; ++half) {
    if (half == 1) {
      __syncthreads();
      stageV(1);
      __syncthreads();
    }
    f32x4 oac[2][4] = {};
#pragma unroll
    for (int kt = 0; kt < 4; ++kt) {
      const int klo = kt * 32 + lhi * 8;
      bf16x8 pa[2], vb[4];
#pragma unroll
      for (int i = 0; i < 2; ++i) pa[i] = *(const bf16x8*)&Ps[wr + i * 16 + l15][klo];
#pragma unroll
      for (int jd = 0; jd < 4; ++jd) vb[jd] = *(const bf16x8*)&Vt[jd * 16 + l15][klo];
#pragma unroll
      for (int i = 0; i < 2; ++i)
#pragma unroll
        for (int jd = 0; jd < 4; ++jd)
          oac[i][jd] = __builtin_amdgcn_mfma_f32_16x16x32_bf16(pa[i], vb[jd], oac[i][jd], 0, 0, 0);
    }
#pragma unroll
    for (int i = 0; i < 2; ++i)
#pragma unroll
      for (int q = 0; q < 4; ++q) {
        const int r = wr + i * 16 + lhi * 4 + q;
        if (r < 120) {
          const float sc = rinv[i][q];
#pragma unroll
          for (int jd = 0; jd < 4; ++jd)
            Ob[(rowbase + r) * 512 + hoff + half * 64 + jd * 16 + l15] = f2b(oac[i][jd][q] * sc);
        }
      }
  }
}

// ---------------------------------------------------------------------------
// Spatial MFMA attention. Block = (f,b) instance (7680 blocks), wave = head.
__global__ __launch_bounds__(256)
void attn_s_k(const unsigned short* __restrict__ Qb, const unsigned short* __restrict__ Kb,
              const unsigned short* __restrict__ Vb, const unsigned short* __restrict__ kts,
              const unsigned short* __restrict__ vts, unsigned short* __restrict__ Ob) {
  __shared__ unsigned short Ps[4][32][34];
  __shared__ unsigned short Vt[4][128][34];
  const int tid = threadIdx.x;
  const int inst = blockIdx.x;
  const int b = inst & (B_DIM - 1);
  const size_t rowbase = (size_t)inst * 22;
  const int lane = tid & 63;
  const int h = tid >> 6;
  const int l15 = lane & 15;
  const int lhi = lane >> 4;
  const int hoff = h * 128;

  for (int e = tid; e < 4096; e += 256) {
    const int h2 = e >> 10;
    const int rem = e & 1023;
    const int key = rem >> 5;
    const int d4 = (rem & 31) << 2;
    us4 v;
    if (key <= 22) {
      const unsigned short* src = (key == 0) ? (vts + b * 512) : (Vb + (rowbase + key - 1) * 512);
      v = *(const us4*)(src + h2 * 128 + d4);
    } else { v.x = 0; v.y = 0; v.z = 0; v.w = 0; }
    Vt[h2][d4 + 0][key] = v.x; Vt[h2][d4 + 1][key] = v.y; Vt[h2][d4 + 2][key] = v.z; Vt[h2][d4 + 3][key] = v.w;
  }

  bf16x8 qa[2][4];
#pragma unroll
  for (int i = 0; i < 2; ++i) {
    const int row = min(i * 16 + l15, 21);
    const unsigned short* qp = Qb + (rowbase + row) * 512 + hoff;
#pragma unroll
    for (int kt = 0; kt < 4; ++kt)
      qa[i][kt] = *(const bf16x8*)(qp + kt * 32 + lhi * 8);
  }

  f32x4 acc[2][2] = {};
#pragma unroll
  for (int kt = 0; kt < 4; ++kt) {
    const int klo = kt * 32 + lhi * 8;
    bf16x8 kb[2];
#pragma unroll
    for (int j = 0; j < 2; ++j) {
      const int key = min(j * 16 + l15, 22);
      const unsigned short* kp = (key == 0) ? (kts + b * 512) : (Kb + (rowbase + key - 1) * 512);
      kb[j] = *(const bf16x8*)(kp + hoff + klo);
    }
#pragma unroll
    for (int i = 0; i < 2; ++i)
#pragma unroll
      for (int j = 0; j < 2; ++j)
        acc[i][j] = __builtin_amdgcn_mfma_f32_16x16x32_bf16(qa[i][kt], kb[j], acc[i][j], 0, 0, 0);
  }

  float rinv[2][4];
#pragma unroll
  for (int i = 0; i < 2; ++i)
#pragma unroll
    for (int q = 0; q < 4; ++q) {
      float m = -1e30f;
#pragma unroll
      for (int j = 0; j < 2; ++j)
        if (j * 16 + l15 <= 22) m = fmaxf(m, acc[i][j][q]);
#pragma unroll
      for (int mk = 1; mk < 16; mk <<= 1) m = fmaxf(m, __shfl_xor(m, mk, 64));
      float s = 0.f;
#pragma unroll
      for (int j = 0; j < 2; ++j) {
        const float e = (j * 16 + l15 <= 22) ? __expf(acc[i][j][q] - m) : 0.f;
        acc[i][j][q] = e; s += e;
      }
#pragma unroll
      for (int mk = 1; mk < 16; mk <<= 1) s += __shfl_xor(s, mk, 64);
      rinv[i][q] = 1.f / s;
    }

#pragma unroll
  for (int i = 0; i < 2; ++i)
#pragma unroll
    for (int j = 0; j < 2; ++j)
#pragma unroll
      for (int q = 0; q < 4; ++q)
        Ps[h][i * 16 + lhi * 4 + q][j * 16 + l15] = f2b(acc[i][j][q]);

  __syncthreads();

  f32x4 oac[2][8] = {};
  {
    const int klo = lhi * 8;
    bf16x8 pa[2];
#pragma unroll
    for (int i = 0; i < 2; ++i) pa[i] = *(const bf16x8*)&Ps[h][i * 16 + l15][klo];
#pragma unroll
    for (int jd = 0; jd < 8; ++jd) {
      const bf16x8 vb = *(const bf16x8*)&Vt[h][jd * 16 + l15][klo];
#pragma unroll
      for (int i = 0; i < 2; ++i)
        oac[i][jd] = __builtin_amdgcn_mfma_f32_16x16x32_bf16(pa[i], vb, oac[i][jd], 0, 0, 0);
    }
  }

#pragma unroll
  for (int i = 0; i < 2; ++i)
#pragma unroll
    for (int q = 0; q < 4; ++q) {
      const int r = i * 16 + lhi * 4 + q;
      if (r < 22) {
        const float sc = rinv[i][q];
#pragma unroll
        for (int jd = 0; jd < 8; ++jd)
          Ob[(rowbase + r) * 512 + hoff + jd * 16 + l15] = f2b(oac[i][jd][q] * sc);
      }
    }
}

// ---------------------------------------------------------------------------
// Row norm (ddof=1, eps on sd), f32 input — fallback path.
__global__ __launch_bounds__(256)
void norm_k(const float* __restrict__ in, float* __restrict__ out,
            unsigned short* __restrict__ outB,
            const float* __restrict__ ga, const float* __restrict__ gb, const int mode) {
  const int r = blockIdx.x * 4 + (threadIdx.x >> 6);
  const int lane = threadIdx.x & 63;
  const float* row = in + (size_t)r * 512;
  const float4 v0 = *(const float4*)&row[lane * 4];
  const float4 v1 = *(const float4*)&row[256 + lane * 4];
  float s = v0.x + v0.y + v0.z + v0.w + v1.x + v1.y + v1.z + v1.w;
  float ss = v0.x * v0.x + v0.y * v0.y + v0.z * v0.z + v0.w * v0.w
           + v1.x * v1.x + v1.y * v1.y + v1.z * v1.z + v1.w * v1.w;
#pragma unroll
  for (int m = 1; m < 64; m <<= 1) { s += __shfl_xor(s, m, 64); ss += __shfl_xor(ss, m, 64); }
  const float mean = s * (1.f / 512.f);
  const float var = (ss - 512.f * mean * mean) * (1.f / 511.f);
  const float inv = 1.f / (sqrtf(fmaxf(var, 0.f)) + 1e-6f);
  int ro;
  if (mode == 0) ro = r;
  else if (mode == 1) {
    const int f = r / (B_DIM * J_DIM);
    const int bb = (r / J_DIM) % B_DIM;
    const int j = r % J_DIM;
    ro = (j * B_DIM + bb) * F_DIM + f;
  } else {
    const int j = r / (B_DIM * F_DIM);
    const int bb = (r / F_DIM) % B_DIM;
    const int f = r % F_DIM;
    ro = (f * B_DIM + bb) * J_DIM + j;
  }
  const float4 g0 = *(const float4*)&ga[lane * 4];
  const float4 g1 = *(const float4*)&ga[256 + lane * 4];
  const float4 h0 = *(const float4*)&gb[lane * 4];
  const float4 h1 = *(const float4*)&gb[256 + lane * 4];
  float4 y0, y1;
  y0.x = g0.x * (v0.x - mean) * inv + h0.x;
  y0.y = g0.y * (v0.y - mean) * inv + h0.y;
  y0.z = g0.z * (v0.z - mean) * inv + h0.z;
  y0.w = g0.w * (v0.w - mean) * inv + h0.w;
  y1.x = g1.x * (v1.x - mean) * inv + h1.x;
  y1.y = g1.y * (v1.y - mean) * inv + h1.y;
  y1.z = g1.z * (v1.z - mean) * inv + h1.z;
  y1.w = g1.w * (v1.w - mean) * inv + h1.w;
  if (out) {
    float* orow = out + (size_t)ro * 512;
    *(float4*)&orow[lane * 4] = y0;
    *(float4*)&orow[256 + lane * 4] = y1;
  }
  if (outB) {
    us4 a, b;
    a.x = f2b(y0.x); a.y = f2b(y0.y); a.z = f2b(y0.z); a.w = f2b(y0.w);
    b.x = f2b(y1.x); b.y = f2b(y1.y); b.z = f2b(y1.z); b.w = f2b(y1.w);
    *(us4*)&outB[(size_t)ro * 512 + lane * 4] = a;
    *(us4*)&outB[(size_t)ro * 512 + 256 + lane * 4] = b;
  }
}

// ---------------------------------------------------------------------------
// Row norm, bf16 input (one us8/lane). Optional f32 out and/or bf16 out.
__global__ __launch_bounds__(256)
void normb_k(const unsigned short* __restrict__ in, float* __restrict__ out,
             unsigned short* __restrict__ outB,
             const float* __restrict__ ga, const float* __restrict__ gb, const int mode) {
  const int r = blockIdx.x * 4 + (threadIdx.x >> 6);
  const int lane = threadIdx.x & 63;
  const us8 wv = *(const us8*)&in[(size_t)r * 512 + lane * 8];
  float v[8];
  float s = 0.f, ss = 0.f;
#pragma unroll
  for (int e = 0; e < 8; ++e) {
    v[e] = b2f((unsigned short)wv[e]);
    s += v[e]; ss += v[e] * v[e];
  }
#pragma unroll
  for (int m = 1; m < 64; m <<= 1) { s += __shfl_xor(s, m, 64); ss += __shfl_xor(ss, m, 64); }
  const float mean = s * (1.f / 512.f);
  const float var = (ss - 512.f * mean * mean) * (1.f / 511.f);
  const float inv = 1.f / (sqrtf(fmaxf(var, 0.f)) + 1e-6f);
  int ro;
  if (mode == 0) ro = r;
  else if (mode == 1) {
    const int f = r / (B_DIM * J_DIM);
    const int bb = (r / J_DIM) % B_DIM;
    const int j = r % J_DIM;
    ro = (j * B_DIM + bb) * F_DIM + f;
  } else {
    const int j = r / (B_DIM * F_DIM);
    const int bb = (r / F_DIM) % B_DIM;
    const int f = r % F_DIM;
    ro = (f * B_DIM + bb) * J_DIM + j;
  }
  const float4 g0 = *(const float4*)&ga[lane * 8];
  const float4 g1 = *(const float4*)&ga[lane * 8 + 4];
  const float4 h0 = *(const float4*)&gb[lane * 8];
  const float4 h1 = *(const float4*)&gb[lane * 8 + 4];
  float y[8];
  y[0] = g0.x * (v[0] - mean) * inv + h0.x;
  y[1] = g0.y * (v[1] - mean) * inv + h0.y;
  y[2] = g0.z * (v[2] - mean) * inv + h0.z;
  y[3] = g0.w * (v[3] - mean) * inv + h0.w;
  y[4] = g1.x * (v[4] - mean) * inv + h1.x;
  y[5] = g1.y * (v[5] - mean) * inv + h1.y;
  y[6] = g1.z * (v[6] - mean) * inv + h1.z;
  y[7] = g1.w * (v[7] - mean) * inv + h1.w;
  if (out) {
    float* orow = out + (size_t)ro * 512 + lane * 8;
    __builtin_nontemporal_store(*(f32x4*)&y[0], (f32x4*)&orow[0]);
    __builtin_nontemporal_store(*(f32x4*)&y[4], (f32x4*)&orow[4]);
  }
  if (outB) {
    us8 o;
#pragma unroll
    for (int e = 0; e < 8; ++e) o[e] = f2b(y[e]);
    __builtin_nontemporal_store(o, (us8*)&outB[(size_t)ro * 512 + lane * 8]);
  }
}

// ---------------------------------------------------------------------------
extern "C" void kernel_launch(void* const* d_in, const int* in_sizes, int n_in,
                              void* d_out, int out_size, void* d_ws, size_t ws_size,
                              hipStream_t stream) {
  const float* x   = (const float*)d_in[0];
  const float* tse = (const float*)d_in[1];
  const float* sWq = (const float*)d_in[5];  const float* sbq = (const float*)d_in[6];
  const float* sWk = (const float*)d_in[7];  const float* sbk = (const float*)d_in[8];
  const float* sWv = (const float*)d_in[9];  const float* sbv = (const float*)d_in[10];
  const float* sWo = (const float*)d_in[11]; const float* sbo = (const float*)d_in[12];
  const float* tWq = (const float*)d_in[13]; const float* tbq = (const float*)d_in[14];
  const float* tWk = (const float*)d_in[15]; const float* tbk = (const float*)d_in[16];
  const float* tWv = (const float*)d_in[17]; const float* tbv = (const float*)d_in[18];
  const float* tWo = (const float*)d_in[19]; const float* tbo = (const float*)d_in[20];
  const float* ffW1 = (const float*)d_in[21]; const float* ffb1 = (const float*)d_in[22];
  const float* ffW2 = (const float*)d_in[23]; const float* ffb2 = (const float*)d_in[24];
  const float* n1a = (const float*)d_in[25]; const float* n1b = (const float*)d_in[26];
  const float* n2a = (const float*)d_in[27]; const float* n2b = (const float*)d_in[28];
  const float* n3a = (const float*)d_in[29]; const float* n3b = (const float*)d_in[30];

  char* p = (char*)d_ws;
  auto carve = [&](size_t bytes) { void* r = (void*)p; p += (bytes + 255) & ~(size_t)255; return r; };

  unsigned short* sQKVt = (unsigned short*)carve((size_t)3 * 512 * 512 * 2);
  unsigned short* sOT   = (unsigned short*)carve((size_t)512 * 512 * 2);
  unsigned short* tQKVt = (unsigned short*)carve((size_t)3 * 512 * 512 * 2);
  unsigned short* tOT   = (unsigned short*)carve((size_t)512 * 512 * 2);
  unsigned short* W1T   = (unsigned short*)carve((size_t)2048 * 512 * 2);
  unsigned short* W2T   = (unsigned short*)carve((size_t)512 * 2048 * 2);
  unsigned short* ktss  = (unsigned short*)carve((size_t)64 * 512 * 2);
  unsigned short* vtss  = (unsigned short*)carve((size_t)64 * 512 * 2);
  unsigned short* ktst  = (unsigned short*)carve((size_t)64 * 512 * 2);
  unsigned short* vtst  = (unsigned short*)carve((size_t)64 * 512 * 2);
  unsigned short* Qb    = (unsigned short*)carve((size_t)M_TOK * 512 * 2);

  unsigned short* Kb = (unsigned short*)d_out;   // K/V bf16 + z1/z2 bf16 alias d_out
  unsigned short* Vb = Kb + (size_t)M_TOK * 512;
  float* outF = (float*)d_out;

  const bool bigws = ws_size >= (size_t)873725952ull;
  float* Rbuf = nullptr;           // small-ws only
  unsigned short* Hb  = nullptr;   // [M][2048] bf16 FF hidden; early life: xb | rb1
  unsigned short* xb  = nullptr;
  unsigned short* rb1 = nullptr;
  if (bigws) {
    Hb = (unsigned short*)carve((size_t)M_TOK * 2048 * 2);
    xb = Hb;
    rb1 = Hb + (size_t)M_TOK * 512;
  } else {
    Rbuf = (float*)carve((size_t)M_TOK * 512 * 4);
  }

  const float QSCALE = 0.08838834764831845f; // 1/sqrt(128)

  {
    dim3 tb(32, 8);
    Tc8Args tc;
    tc.W[0] = sWq; tc.WT[0] = sQKVt;
    tc.W[1] = sWk; tc.WT[1] = sQKVt + 262144;
    tc.W[2] = sWv; tc.WT[2] = sQKVt + 524288;
    tc.W[3] = sWo; tc.WT[3] = sOT;
    tc.W[4] = tWq; tc.WT[4] = tQKVt;
    tc.W[5] = tWk; tc.WT[5] = tQKVt + 262144;
    tc.W[6] = tWv; tc.WT[6] = tQKVt + 524288;
    tc.W[7] = tWo; tc.WT[7] = tOT;
    tcast8_k<<<dim3(16, 16, 8), tb, 0, stream>>>(tc);
    tcast_k<<<dim3(64, 16), tb, 0, stream>>>(ffW1, W1T, 512, 2048);
    tcast_k<<<dim3(16, 64), tb, 0, stream>>>(ffW2, W2T, 2048, 512);
  }
  {
    TsArgs ta;
    ta.W[0] = sWk; ta.bias[0] = sbk; ta.out[0] = ktss;
    ta.W[1] = sWv; ta.bias[1] = sbv; ta.out[1] = vtss;
    ta.W[2] = tWk; ta.bias[2] = tbk; ta.out[2] = ktst;
    ta.W[3] = tWv; ta.bias[3] = tbv; ta.out[3] = vtst;
    tsproj_k<<<dim3(B_DIM, 2, 4), 1024, 0, stream>>>(tse, ta);
  }

  const int MT = M_TOK / 128;   // 1320 (fallback grids)
  const int MT2 = M_TOK / 256;  // 660  (256-row tiles; all grids %8==0)

  if (bigws) {
    // ---- spatial attention ----
    cast_k<<<2048, 256, 0, stream>>>(x, xb, M_TOK * 512 / 8);
    gemm256_k<EPI_QKV><<<12 * MT2, 512, 0, stream>>>(
        xb, sQKVt, sbq, sbk, sbv, nullptr, nullptr, Qb, Kb, Vb, 512, 512, 512, 512, 12, QSCALE);
    attn_s_k<<<dim3(F_DIM * B_DIM), 256, 0, stream>>>(Qb, Kb, Vb, ktss, vtss, Qb);
    // z1 = attnO@sWo + sbo + xb -> bf16 into Kb (K dead after attn_s; xb live)
    gemm256_k<EPI_RBB><<<4 * MT2, 512, 0, stream>>>(
        Qb, sOT, sbo, nullptr, nullptr, xb, nullptr, Kb, nullptr, nullptr, 512, 512, 512, 512, 4, 1.f);
    normb_k<<<M_TOK / 4, 256, 0, stream>>>(Kb, nullptr, rb1, n1a, n1b, 1);

    // ---- temporal attention ----
    gemm256_k<EPI_QKV><<<12 * MT2, 512, 0, stream>>>(
        rb1, tQKVt, tbq, tbk, tbv, nullptr, nullptr, Qb, Kb, Vb, 512, 512, 512, 512, 12, QSCALE);
    attn_t_k<<<dim3(J_DIM * B_DIM * H_DIM), 256, 0, stream>>>(Qb, Kb, Vb, ktst, vtst, Qb);
    // z2 = attnO@tWo + tbo + rb1 -> bf16 into Kb (K dead after attn_t)
    gemm256_k<EPI_RBB><<<4 * MT2, 512, 0, stream>>>(
        Qb, tOT, tbo, nullptr, nullptr, rb1, nullptr, Kb, nullptr, nullptr, 512, 512, 512, 512, 4, 1.f);
    normb_k<<<M_TOK / 4, 256, 0, stream>>>(Kb, nullptr, Qb, n2a, n2b, 2);

    // ---- feed-forward: gelu + K=2048 proj; z3 in-place in Qb ----
    gemm256_k<EPI_GELU><<<16 * MT2, 512, 0, stream>>>(
        Qb, W1T, ffb1, nullptr, nullptr, nullptr, nullptr, Hb, nullptr, nullptr,
        512, 512, 2048, 512, 16, 1.f);
    gemm256_k<EPI_RBB><<<4 * MT2, 512, 0, stream>>>(
        Hb, W2T, ffb2, nullptr, nullptr, Qb, nullptr, Qb, nullptr, nullptr,
        2048, 2048, 512, 2048, 4, 1.f);
    normb_k<<<M_TOK / 4, 256, 0, stream>>>(Qb, outF, nullptr, n3a, n3b, 0);
  } else {
    // ---- small-ws fallback (round-6 flow, f32 z-chain) ----
    gemmf_k<EPI_QKV><<<12 * MT, 256, 0, stream>>>(
        x, sQKVt, sbq, sbk, sbv, nullptr, nullptr, Qb, Kb, Vb, 512, 512, 512, 512, 12, QSCALE);
    attn_s_k<<<dim3(F_DIM * B_DIM), 256, 0, stream>>>(Qb, Kb, Vb, ktss, vtss, Qb);
    gemm_k<EPI_RES><<<4 * MT, 256, 0, stream>>>(
        Qb, sOT, sbo, nullptr, nullptr, x, outF, nullptr, nullptr, nullptr, 512, 512, 512, 512, 4, 1.f);
    norm_k<<<M_TOK / 4, 256, 0, stream>>>(outF, Rbuf, nullptr, n1a, n1b, 1);

    gemmf_k<EPI_QKV><<<12 * MT, 256, 0, stream>>>(
        Rbuf, tQKVt, tbq, tbk, tbv, nullptr, nullptr, Qb, Kb, Vb, 512, 512, 512, 512, 12, QSCALE);
    attn_t_k<<<dim3(J_DIM * B_DIM * H_DIM), 256, 0, stream>>>(Qb, Kb, Vb, ktst, vtst, Qb);
    gemm_k<EPI_RES><<<4 * MT, 256, 0, stream>>>(
        Qb, tOT, tbo, nullptr, nullptr, Rbuf, outF, nullptr, nullptr, nullptr, 512, 512, 512, 512, 4, 1.f);
    norm_k<<<M_TOK / 4, 256, 0, stream>>>(outF, Rbuf, Qb, n2a, n2b, 2);

    for (int c = 0; c < 4; ++c) {
      gemm_k<EPI_GELU><<<4 * MT, 256, 0, stream>>>(
          Qb, W1T + (size_t)c * 512 * 512, ffb1 + c * 512, nullptr, nullptr,
          nullptr, nullptr, Qb, nullptr, nullptr, 512, 512, 512, 512, 4, 1.f);
      if (c == 0)
        gemm_k<EPI_RES><<<4 * MT, 256, 0, stream>>>(
            Qb, W2T + c * 512, ffb2, nullptr, nullptr, Rbuf, outF,
            nullptr, nullptr, nullptr, 512, 2048, 512, 512, 4, 1.f);
      else
        gemm_k<EPI_ACC><<<4 * MT, 256, 0, stream>>>(
            Qb, W2T + c * 512, nullptr, nullptr, nullptr, nullptr, outF,
            nullptr, nullptr, nullptr, 512, 2048, 512, 512, 4, 1.f);
    }
    norm_k<<<M_TOK / 4, 256, 0, stream>>>(outF, outF, nullptr, n3a, n3b, 0);
  }
}

// Round 14
// 2981.829 us; speedup vs baseline: 1.1988x; 1.1988x over previous
//
#include <hip/hip_runtime.h>
#include <hip/hip_bf16.h>
#include <math.h>

// TransformerDecoder2dLayer on MI355X (gfx950).
// Round 14: fix round-13 race — staged epilogue used RAW s_barrier between
// ds_write phase and cross-thread LDS reads (no waitcnt/fence semantics ->
// stale reads, absmax 1.01). Replaced with __syncthreads(). Rest identical.

#define F_DIM 120
#define B_DIM 64
#define J_DIM 22
#define H_DIM 4
#define M_TOK (F_DIM * B_DIM * J_DIM) // 168960

#define DEV static __device__ __forceinline__

typedef short bf16x8 __attribute__((ext_vector_type(8)));
typedef short us8 __attribute__((ext_vector_type(8)));
typedef float f32x4 __attribute__((ext_vector_type(4)));

struct __align__(8) us4 { unsigned short x, y, z, w; };

DEV unsigned short f2b(float f) {
  unsigned u = __float_as_uint(f);
  u += 0x7fffu + ((u >> 16) & 1u);
  return (unsigned short)(u >> 16);
}
DEV float b2f(unsigned short u) { return __uint_as_float(((unsigned)u) << 16); }

#define GLOAD16(g, l)                                                          \
  __builtin_amdgcn_global_load_lds(                                            \
      (const __attribute__((address_space(1))) void*)(g),                      \
      (__attribute__((address_space(3))) void*)(l), 16, 0, 0)

enum { EPI_QKV = 0, EPI_GELU = 1, EPI_RES = 2, EPI_ACC = 3, EPI_RESB = 4,
       EPI_ROB = 5, EPI_RBB = 6 };

// ---------------------------------------------------------------------------
__global__ __launch_bounds__(256)
void cast_k(const float* __restrict__ in, unsigned short* __restrict__ out, int n8) {
  for (int i = blockIdx.x * 256 + threadIdx.x; i < n8; i += gridDim.x * 256) {
    const float4 a = ((const float4*)in)[i * 2];
    const float4 b = ((const float4*)in)[i * 2 + 1];
    us8 v;
    v[0] = f2b(a.x); v[1] = f2b(a.y); v[2] = f2b(a.z); v[3] = f2b(a.w);
    v[4] = f2b(b.x); v[5] = f2b(b.y); v[6] = f2b(b.z); v[7] = f2b(b.w);
    __builtin_nontemporal_store(v, (us8*)&out[i * 8]);
  }
}

// ---------------------------------------------------------------------------
__global__ __launch_bounds__(256)
void tcast_k(const float* __restrict__ W, unsigned short* __restrict__ WT, int K, int N) {
  __shared__ float t[32][33];
  const int n0 = blockIdx.x * 32, k0 = blockIdx.y * 32;
  const int tx = threadIdx.x, ty = threadIdx.y;
#pragma unroll
  for (int i = 0; i < 4; ++i)
    t[ty + i * 8][tx] = W[(size_t)(k0 + ty + i * 8) * N + n0 + tx];
  __syncthreads();
#pragma unroll
  for (int i = 0; i < 4; ++i)
    WT[(size_t)(n0 + ty + i * 8) * K + k0 + tx] = f2b(t[tx][ty + i * 8]);
}

struct Tc8Args { const float* W[8]; unsigned short* WT[8]; };
__global__ __launch_bounds__(256)
void tcast8_k(Tc8Args a) {
  __shared__ float t[32][33];
  const float* W = a.W[blockIdx.z];
  unsigned short* WT = a.WT[blockIdx.z];
  const int n0 = blockIdx.x * 32, k0 = blockIdx.y * 32;
  const int tx = threadIdx.x, ty = threadIdx.y;
#pragma unroll
  for (int i = 0; i < 4; ++i)
    t[ty + i * 8][tx] = W[(size_t)(k0 + ty + i * 8) * 512 + n0 + tx];
  __syncthreads();
#pragma unroll
  for (int i = 0; i < 4; ++i)
    WT[(size_t)(n0 + ty + i * 8) * 512 + k0 + tx] = f2b(t[tx][ty + i * 8]);
}

// ---------------------------------------------------------------------------
struct TsArgs { const float* W[4]; const float* bias[4]; unsigned short* out[4]; };
__global__ __launch_bounds__(1024)
void tsproj_k(const float* __restrict__ ts, TsArgs a) {
  __shared__ float tsr[512];
  __shared__ float red[3][256];
  const int b = blockIdx.x;
  const int nb = blockIdx.y;
  const int pj = blockIdx.z;
  const int t = threadIdx.x;
  const int n = nb * 256 + (t & 255);
  const int kh = t >> 8;
  if (t < 512) tsr[t] = ts[b * 512 + t];
  __syncthreads();
  const float* W = a.W[pj];
  float acc = 0.f;
  const int k0 = kh * 128;
  for (int k = k0; k < k0 + 128; ++k)
    acc += tsr[k] * W[(size_t)k * 512 + n];
  if (kh) red[kh - 1][t & 255] = acc;
  __syncthreads();
  if (kh == 0) {
    acc += red[0][t & 255] + red[1][t & 255] + red[2][t & 255];
    a.out[pj][b * 512 + n] = f2b(acc + a.bias[pj][n]);
  }
}

// ---------------------------------------------------------------------------
// Scalar epilogue op — used by fallback kernels only. Plain loads/stores.
template<int EPI>
DEV void epi_store(float v, int row, int col, const float* b0, const float* b1,
                   const float* b2, const void* res, float* outF,
                   unsigned short* o0, unsigned short* o1, unsigned short* o2,
                   int ldo, float scale) {
  if constexpr (EPI == EPI_QKV) {
    const int seg = col >> 9;
    const int cl = col & 511;
    const float* bs = (seg == 0) ? b0 : (seg == 1) ? b1 : b2;
    unsigned short* ob = (seg == 0) ? o0 : (seg == 1) ? o1 : o2;
    const float sc = (seg == 0) ? scale : 1.f;
    v = (v + bs[cl]) * sc;
    ob[(size_t)row * 512 + cl] = f2b(v);
  } else if constexpr (EPI == EPI_GELU) {
    v += b0[col];
    const float a2 = 1.5957691216057308f * (v + 0.044715f * v * v * v);
    const float g = v / (1.f + __expf(-a2));
    o0[(size_t)row * ldo + col] = f2b(g);
  } else if constexpr (EPI == EPI_RES) {
    const size_t off = (size_t)row * 512 + col;
    outF[off] = v + b0[col] + ((const float*)res)[off];
  } else if constexpr (EPI == EPI_RESB) {
    const size_t off = (size_t)row * 512 + col;
    outF[off] = v + b0[col] + b2f(((const unsigned short*)res)[off]);
  } else if constexpr (EPI == EPI_ROB) {
    const size_t off = (size_t)row * 512 + col;
    o0[off] = f2b(v + b0[col] + ((const float*)res)[off]);
  } else if constexpr (EPI == EPI_RBB) {
    const size_t off = (size_t)row * 512 + col;
    o0[off] = f2b(v + b0[col] + b2f(((const unsigned short*)res)[off]));
  } else { // EPI_ACC
    const size_t off = (size_t)row * 512 + col;
    outF[off] = v + outF[off];
  }
}

// ---------------------------------------------------------------------------
// 256x128 GEMM, BK=32, 8 waves (4m x 2n) of 64x64; triple-buffered LDS,
// counted vmcnt(3), 1 s_barrier/step. Epilogue (QKV/GELU/RBB): stage bf16
// output tile in dead LDS (granule-XOR swizzle), stream out as us8 nt stores.
// Sync between ds_write phase and cross-thread reads = __syncthreads()
// (raw s_barrier has no fence semantics -> round-13 race).
template<int EPI>
__global__ __launch_bounds__(512, 4)
void gemm256_k(const unsigned short* __restrict__ Ab, const unsigned short* __restrict__ Wt,
               const float* __restrict__ b0, const float* __restrict__ b1, const float* __restrict__ b2,
               const void* __restrict__ res, float* __restrict__ outF,
               unsigned short* __restrict__ o0, unsigned short* __restrict__ o1, unsigned short* __restrict__ o2,
               int lda, int ldw, int ldo, int nk, int nx, float scale) {
  __shared__ unsigned short As[3][8192];   // 256 x 32 (x3) ; reused as Ot post-loop
  __shared__ unsigned short Bs[3][4096];
  const int tid = threadIdx.x;
  const int chunkg = gridDim.x >> 3;       // XCD-chunked bijective swizzle (nwg%8==0)
  const int wg = (blockIdx.x & 7) * chunkg + (blockIdx.x >> 3);
  const int nbase = (wg % nx) * 128;
  const int mbase = (wg / nx) * 256;
  const int lane = tid & 63;
  const int w = tid >> 6;
  const int wr = (w >> 1) * 64;
  const int wc = (w & 1) * 64;
  const int l15 = lane & 15;
  const int lhi = lane >> 4;

  const int crow = lane >> 2;
  const int ccol = (((lane & 3) ^ ((lane >> 3) & 3)) << 3);
  const unsigned short* gA0 = Ab + (size_t)(mbase + 32 * w + crow) * lda + ccol;
  const unsigned short* gA1 = gA0 + (size_t)16 * lda;
  const unsigned short* gB0 = Wt + (size_t)(nbase + 16 * w + crow) * ldw + ccol;

  auto stage = [&](int bb, int kt) {   // 3 vmem ops / wave
    GLOAD16(gA0 + kt, &As[bb][(2 * w) * 512]);
    GLOAD16(gA1 + kt, &As[bb][(2 * w + 1) * 512]);
    GLOAD16(gB0 + kt, &Bs[bb][w * 512]);
  };

  f32x4 acc[4][4] = {};
  const int KT = nk >> 5;
  const int swz = ((lhi ^ ((l15 >> 1) & 3)) << 3);

  stage(0, 0);
  stage(1, 32);
  asm volatile("s_waitcnt vmcnt(3)" ::: "memory");
  __builtin_amdgcn_s_barrier();

  for (int t = 0; t < KT; ++t) {
    const unsigned short* as = As[t % 3];
    const unsigned short* bs = Bs[t % 3];
    if (t + 2 < KT) stage((t + 2) % 3, (t + 2) << 5);
    bf16x8 afr[4], bfr[4];
#pragma unroll
    for (int i = 0; i < 4; ++i) afr[i] = *(const bf16x8*)&as[(wr + i * 16 + l15) * 32 + swz];
#pragma unroll
    for (int j = 0; j < 4; ++j) bfr[j] = *(const bf16x8*)&bs[(wc + j * 16 + l15) * 32 + swz];
#pragma unroll
    for (int i = 0; i < 4; ++i)
#pragma unroll
      for (int j = 0; j < 4; ++j)
        acc[i][j] = __builtin_amdgcn_mfma_f32_16x16x32_bf16(afr[i], bfr[j], acc[i][j], 0, 0, 0);
    if (t + 2 < KT)      asm volatile("s_waitcnt vmcnt(3) lgkmcnt(0)" ::: "memory");
    else if (t + 1 < KT) asm volatile("s_waitcnt vmcnt(0) lgkmcnt(0)" ::: "memory");
    else                 asm volatile("s_waitcnt lgkmcnt(0)" ::: "memory");
    __builtin_amdgcn_s_barrier();
  }

  if constexpr (EPI == EPI_QKV || EPI == EPI_GELU || EPI == EPI_RBB) {
    // ---- staged vectorized epilogue ----
    unsigned short* Ot = &As[0][0];   // 24576 shorts free; need 16384/half
    const int seg = (EPI == EPI_QKV) ? (nbase >> 9) : 0;   // tile fits one segment
    unsigned short* ob = (EPI == EPI_QKV) ? ((seg == 0) ? o0 : (seg == 1) ? o1 : o2) : o0;
    const float* bb = (EPI == EPI_QKV) ? ((seg == 0) ? b0 : (seg == 1) ? b1 : b2) : b0;
    const float sc = (EPI == EPI_QKV && 0 == seg) ? scale : 1.f;
    const int cb = (EPI == EPI_QKV) ? (nbase & 511) : nbase;
#pragma unroll
    for (int mh = 0; mh < 2; ++mh) {
      if ((w >> 2) == mh) {   // waves owning rows [mh*128, mh*128+128)
        const int lwr = ((w >> 1) & 1) * 64;
#pragma unroll
        for (int i = 0; i < 4; ++i)
#pragma unroll
          for (int j = 0; j < 4; ++j) {
            const int c = wc + j * 16 + l15;
#pragma unroll
            for (int q = 0; q < 4; ++q) {
              const int lrow = lwr + i * 16 + (lhi << 2) + q;
              float v = acc[i][j][q];
              if constexpr (EPI == EPI_QKV) {
                v = (v + bb[cb + c]) * sc;
              } else if constexpr (EPI == EPI_GELU) {
                v += bb[cb + c];
                const float a2 = 1.5957691216057308f * (v + 0.044715f * v * v * v);
                v = v / (1.f + __expf(-a2));
              } else {  // RBB: bias now, residual in stream phase
                v += bb[cb + c];
              }
              Ot[(lrow << 7) + ((((c >> 3) ^ (lrow & 7)) << 3) | (c & 7))] = f2b(v);
            }
          }
      }
      __syncthreads();   // full fence: ds_writes visible to all threads
#pragma unroll
      for (int ps = 0; ps < 4; ++ps) {   // 4 x 512 thr x 16B = 32KB half-tile
        const int idx = (ps * 512 + tid) * 8;
        const int row = idx >> 7;
        const int c = idx & 127;
        us8 val = *(const us8*)&Ot[(row << 7) + (((c >> 3) ^ (row & 7)) << 3)];
        const size_t grow = (size_t)(mbase + mh * 128 + row);
        const int gcol = cb + c;
        if constexpr (EPI == EPI_RBB) {
          const us8 r = __builtin_nontemporal_load(
              (const us8*)&((const unsigned short*)res)[grow * 512 + gcol]);
#pragma unroll
          for (int e = 0; e < 8; ++e)
            val[e] = (short)f2b(b2f((unsigned short)val[e]) + b2f((unsigned short)r[e]));
        }
        __builtin_nontemporal_store(val, (us8*)&ob[grow * ldo + gcol]);
      }
      __syncthreads();   // reads of Ot retired before next mh overwrites
    }
  } else {
#pragma unroll
    for (int i = 0; i < 4; ++i)
#pragma unroll
      for (int j = 0; j < 4; ++j) {
        const int row0 = mbase + wr + i * 16 + (lhi << 2);
        const int col = nbase + wc + j * 16 + l15;
#pragma unroll
        for (int q = 0; q < 4; ++q)
          epi_store<EPI>(acc[i][j][q], row0 + q, col, b0, b1, b2, res, outF, o0, o1, o2, ldo, scale);
      }
  }
}

// ---------------------------------------------------------------------------
// 128x128 pipelined GEMM — small-ws fallback path.
template<int EPI>
__global__ __launch_bounds__(256)
void gemm_k(const unsigned short* __restrict__ Ab, const unsigned short* __restrict__ Wt,
            const float* __restrict__ b0, const float* __restrict__ b1, const float* __restrict__ b2,
            const void* __restrict__ res, float* __restrict__ outF,
            unsigned short* __restrict__ o0, unsigned short* __restrict__ o1, unsigned short* __restrict__ o2,
            int lda, int ldw, int ldo, int nk, int nx, float scale) {
  __shared__ unsigned short As[3][4096];
  __shared__ unsigned short Bs[3][4096];
  const int tid = threadIdx.x;
  const int chunkg = gridDim.x >> 3;
  const int wg = (blockIdx.x & 7) * chunkg + (blockIdx.x >> 3);
  const int nbase = (wg % nx) * 128;
  const int mbase = (wg / nx) * 128;
  const int lane = tid & 63;
  const int w = tid >> 6;
  const int wr = (w >> 1) * 64;
  const int wc = (w & 1) * 64;
  const int l15 = lane & 15;
  const int lhi = lane >> 4;

  const int crow = lane >> 2;
  const int ccol = (((lane & 3) ^ ((lane >> 3) & 3)) << 3);
  const unsigned short* gA0 = Ab + (size_t)(mbase + 32 * w + crow) * lda + ccol;
  const unsigned short* gA1 = gA0 + (size_t)16 * lda;
  const unsigned short* gB0 = Wt + (size_t)(nbase + 32 * w + crow) * ldw + ccol;
  const unsigned short* gB1 = gB0 + (size_t)16 * ldw;

  auto stage = [&](int bb, int kt) {
    GLOAD16(gA0 + kt, &As[bb][(2 * w) * 512]);
    GLOAD16(gA1 + kt, &As[bb][(2 * w + 1) * 512]);
    GLOAD16(gB0 + kt, &Bs[bb][(2 * w) * 512]);
    GLOAD16(gB1 + kt, &Bs[bb][(2 * w + 1) * 512]);
  };

  f32x4 acc[4][4] = {};
  const int KT = nk >> 5;
  const int swz = ((lhi ^ ((l15 >> 1) & 3)) << 3);

  stage(0, 0);
  stage(1, 32);
  asm volatile("s_waitcnt vmcnt(4)" ::: "memory");
  __builtin_amdgcn_s_barrier();

  for (int t = 0; t < KT; ++t) {
    const unsigned short* as = As[t % 3];
    const unsigned short* bs = Bs[t % 3];
    if (t + 2 < KT) stage((t + 2) % 3, (t + 2) << 5);
    bf16x8 afr[4], bfr[4];
#pragma unroll
    for (int i = 0; i < 4; ++i) afr[i] = *(const bf16x8*)&as[(wr + i * 16 + l15) * 32 + swz];
#pragma unroll
    for (int j = 0; j < 4; ++j) bfr[j] = *(const bf16x8*)&bs[(wc + j * 16 + l15) * 32 + swz];
#pragma unroll
    for (int i = 0; i < 4; ++i)
#pragma unroll
      for (int j = 0; j < 4; ++j)
        acc[i][j] = __builtin_amdgcn_mfma_f32_16x16x32_bf16(afr[i], bfr[j], acc[i][j], 0, 0, 0);
    if (t + 2 < KT)      asm volatile("s_waitcnt vmcnt(4) lgkmcnt(0)" ::: "memory");
    else if (t + 1 < KT) asm volatile("s_waitcnt vmcnt(0) lgkmcnt(0)" ::: "memory");
    else                 asm volatile("s_waitcnt lgkmcnt(0)" ::: "memory");
    __builtin_amdgcn_s_barrier();
  }

#pragma unroll
  for (int i = 0; i < 4; ++i)
#pragma unroll
    for (int j = 0; j < 4; ++j) {
      const int row0 = mbase + wr + i * 16 + (lhi << 2);
      const int col = nbase + wc + j * 16 + l15;
#pragma unroll
      for (int q = 0; q < 4; ++q)
        epi_store<EPI>(acc[i][j][q], row0 + q, col, b0, b1, b2, res, outF, o0, o1, o2, ldo, scale);
    }
}

// ---------------------------------------------------------------------------
// Legacy reg-staging GEMM for f32 A (small-ws fallback only).
template<int EPI>
__global__ __launch_bounds__(256)
void gemmf_k(const float* __restrict__ Af, const unsigned short* __restrict__ Wt,
             const float* __restrict__ b0, const float* __restrict__ b1, const float* __restrict__ b2,
             const void* __restrict__ res, float* __restrict__ outF,
             unsigned short* __restrict__ o0, unsigned short* __restrict__ o1, unsigned short* __restrict__ o2,
             int lda, int ldw, int ldo, int nk, int nx, float scale) {
  __shared__ unsigned short As[128][40];
  __shared__ unsigned short Bs[128][40];
  const int tid = threadIdx.x;
  const int chunkg = gridDim.x >> 3;
  const int wg = (blockIdx.x & 7) * chunkg + (blockIdx.x >> 3);
  const int nbase = (wg % nx) * 128;
  const int mbase = (wg / nx) * 128;
  const int lane = tid & 63;
  const int w = tid >> 6;
  const int wr = (w >> 1) * 64;
  const int wc = (w & 1) * 64;
  const int l15 = lane & 15;
  const int lhi = lane >> 4;

  float4 ra[4];
  us4 rb[4];
  auto loadAB = [&](int kt) {
#pragma unroll
    for (int i = 0; i < 4; ++i) {
      const int g = i * 256 + tid;
      const int r = g >> 3;
      const int c = (g & 7) << 2;
      ra[i] = *(const float4*)(Af + (size_t)(mbase + r) * lda + kt + c);
      rb[i] = *(const us4*)(Wt + (size_t)(nbase + r) * ldw + kt + c);
    }
  };
  auto storeAB = [&]() {
#pragma unroll
    for (int i = 0; i < 4; ++i) {
      const int g = i * 256 + tid;
      const int r = g >> 3;
      const int c = (g & 7) << 2;
      us4 ua;
      ua.x = f2b(ra[i].x); ua.y = f2b(ra[i].y); ua.z = f2b(ra[i].z); ua.w = f2b(ra[i].w);
      *(us4*)&As[r][c] = ua;
      *(us4*)&Bs[r][c] = rb[i];
    }
  };

  f32x4 acc[4][4] = {};
  const int KT = nk >> 5;
  loadAB(0);
  storeAB();
  __syncthreads();
  for (int t = 0; t < KT; ++t) {
    if (t + 1 < KT) loadAB((t + 1) << 5);
    bf16x8 afr[4], bfr[4];
    const int klo = lhi << 3;
#pragma unroll
    for (int i = 0; i < 4; ++i) afr[i] = *(const bf16x8*)&As[wr + i * 16 + l15][klo];
#pragma unroll
    for (int j = 0; j < 4; ++j) bfr[j] = *(const bf16x8*)&Bs[wc + j * 16 + l15][klo];
#pragma unroll
    for (int i = 0; i < 4; ++i)
#pragma unroll
      for (int j = 0; j < 4; ++j)
        acc[i][j] = __builtin_amdgcn_mfma_f32_16x16x32_bf16(afr[i], bfr[j], acc[i][j], 0, 0, 0);
    __syncthreads();
    if (t + 1 < KT) { storeAB(); __syncthreads(); }
  }

#pragma unroll
  for (int i = 0; i < 4; ++i)
#pragma unroll
    for (int j = 0; j < 4; ++j) {
      const int row0 = mbase + wr + i * 16 + (lhi << 2);
      const int col = nbase + wc + j * 16 + l15;
#pragma unroll
      for (int q = 0; q < 4; ++q)
        epi_store<EPI>(acc[i][j][q], row0 + q, col, b0, b1, b2, res, outF, o0, o1, o2, ldo, scale);
    }
}

// ---------------------------------------------------------------------------
// Temporal MFMA attention. Block = (instance, head): 1408*4 blocks, 4 waves.
__global__ __launch_bounds__(256)
void attn_t_k(const unsigned short* __restrict__ Qb, const unsigned short* __restrict__ Kb,
              const unsigned short* __restrict__ Vb, const unsigned short* __restrict__ kts,
              const unsigned short* __restrict__ vts, unsigned short* __restrict__ Ob) {
  __shared__ unsigned short Ps[128][134];
  __shared__ unsigned short Vt[64][134];
  const int tid = threadIdx.x;
  const int inst = blockIdx.x >> 2;
  const int h = blockIdx.x & 3;
  const int b = inst & (B_DIM - 1);
  const size_t rowbase = (size_t)inst * 120;
  const int hoff = h * 128;
  const int lane = tid & 63;
  const int w = tid >> 6;
  const int wr = w * 32;
  const int l15 = lane & 15;
  const int lhi = lane >> 4;

  auto stageV = [&](int half) {
    for (int e = tid; e < 2048; e += 256) {
      const int d4 = (e & 15) << 2;
      const int key = e >> 4;
      us4 v;
      if (key <= 120) {
        const unsigned short* src = (key == 0) ? (vts + b * 512) : (Vb + (rowbase + key - 1) * 512);
        v = *(const us4*)(src + hoff + half * 64 + d4);
      } else { v.x = 0; v.y = 0; v.z = 0; v.w = 0; }
      Vt[d4 + 0][key] = v.x; Vt[d4 + 1][key] = v.y; Vt[d4 + 2][key] = v.z; Vt[d4 + 3][key] = v.w;
    }
  };
  stageV(0);

  bf16x8 qa[2][4];
#pragma unroll
  for (int i = 0; i < 2; ++i) {
    const int row = min(wr + i * 16 + l15, 119);
    const unsigned short* qp = Qb + (rowbase + row) * 512 + hoff;
#pragma unroll
    for (int kt = 0; kt < 4; ++kt)
      qa[i][kt] = *(const bf16x8*)(qp + kt * 32 + lhi * 8);
  }

  f32x4 acc[2][8] = {};
#pragma unroll
  for (int kt = 0; kt < 4; ++kt) {
    const int klo = kt * 32 + lhi * 8;
    bf16x8 kb[8];
#pragma unroll
    for (int j = 0; j < 8; ++j) {
      const int key = min(j * 16 + l15, 120);
      const unsigned short* kp = (key == 0) ? (kts + b * 512) : (Kb + (rowbase + key - 1) * 512);
      kb[j] = *(const bf16x8*)(kp + hoff + klo);
    }
#pragma unroll
    for (int i = 0; i < 2; ++i)
#pragma unroll
      for (int j = 0; j < 8; ++j)
        acc[i][j] = __builtin_amdgcn_mfma_f32_16x16x32_bf16(qa[i][kt], kb[j], acc[i][j], 0, 0, 0);
  }

  float rinv[2][4];
#pragma unroll
  for (int i = 0; i < 2; ++i)
#pragma unroll
    for (int q = 0; q < 4; ++q) {
      float m = -1e30f;
#pragma unroll
      for (int j = 0; j < 8; ++j)
        if (j * 16 + l15 <= 120) m = fmaxf(m, acc[i][j][q]);
#pragma unroll
      for (int mk = 1; mk < 16; mk <<= 1) m = fmaxf(m, __shfl_xor(m, mk, 64));
      float s = 0.f;
#pragma unroll
      for (int j = 0; j < 8; ++j) {
        const float e = (j * 16 + l15 <= 120) ? __expf(acc[i][j][q] - m) : 0.f;
        acc[i][j][q] = e; s += e;
      }
#pragma unroll
      for (int mk = 1; mk < 16; mk <<= 1) s += __shfl_xor(s, mk, 64);
      rinv[i][q] = 1.f / s;
    }

#pragma unroll
  for (int i = 0; i < 2; ++i)
#pragma unroll
    for (int j = 0; j < 8; ++j)
#pragma unroll
      for (int q = 0; q < 4; ++q)
        Ps[wr + i * 16 + lhi * 4 + q][j * 16 + l15] = f2b(acc[i][j][q]);

  __syncthreads();

#pragma unroll
  for (int half = 0; half < 2; ++half) {
    if (half == 1) {
      __syncthreads();
      stageV(1);
      __syncthreads();
    }
    f32x4 oac[2][4] = {};
#pragma unroll
    for (int kt = 0; kt < 4; ++kt) {
      const int klo = kt * 32 + lhi * 8;
      bf16x8 pa[2], vb[4];
#pragma unroll
      for (int i = 0; i < 2; ++i) pa[i] = *(const bf16x8*)&Ps[wr + i * 16 + l15][klo];
#pragma unroll
      for (int jd = 0; jd < 4; ++jd) vb[jd] = *(const bf16x8*)&Vt[jd * 16 + l15][klo];
#pragma unroll
      for (int i = 0; i < 2; ++i)
#pragma unroll
        for (int jd = 0; jd < 4; ++jd)
          oac[i][jd] = __builtin_amdgcn_mfma_f32_16x16x32_bf16(pa[i], vb[jd], oac[i][jd], 0, 0, 0);
    }
#pragma unroll
    for (int i = 0; i < 2; ++i)
#pragma unroll
      for (int q = 0; q < 4; ++q) {
        const int r = wr + i * 16 + lhi * 4 + q;
        if (r < 120) {
          const float sc = rinv[i][q];
#pragma unroll
          for (int jd = 0; jd < 4; ++jd)
            Ob[(rowbase + r) * 512 + hoff + half * 64 + jd * 16 + l15] = f2b(oac[i][jd][q] * sc);
        }
      }
  }
}

// ---------------------------------------------------------------------------
// Spatial MFMA attention. Block = (f,b) instance (7680 blocks), wave = head.
__global__ __launch_bounds__(256)
void attn_s_k(const unsigned short* __restrict__ Qb, const unsigned short* __restrict__ Kb,
              const unsigned short* __restrict__ Vb, const unsigned short* __restrict__ kts,
              const unsigned short* __restrict__ vts, unsigned short* __restrict__ Ob) {
  __shared__ unsigned short Ps[4][32][34];
  __shared__ unsigned short Vt[4][128][34];
  const int tid = threadIdx.x;
  const int inst = blockIdx.x;
  const int b = inst & (B_DIM - 1);
  const size_t rowbase = (size_t)inst * 22;
  const int lane = tid & 63;
  const int h = tid >> 6;
  const int l15 = lane & 15;
  const int lhi = lane >> 4;
  const int hoff = h * 128;

  for (int e = tid; e < 4096; e += 256) {
    const int h2 = e >> 10;
    const int rem = e & 1023;
    const int key = rem >> 5;
    const int d4 = (rem & 31) << 2;
    us4 v;
    if (key <= 22) {
      const unsigned short* src = (key == 0) ? (vts + b * 512) : (Vb + (rowbase + key - 1) * 512);
      v = *(const us4*)(src + h2 * 128 + d4);
    } else { v.x = 0; v.y = 0; v.z = 0; v.w = 0; }
    Vt[h2][d4 + 0][key] = v.x; Vt[h2][d4 + 1][key] = v.y; Vt[h2][d4 + 2][key] = v.z; Vt[h2][d4 + 3][key] = v.w;
  }

  bf16x8 qa[2][4];
#pragma unroll
  for (int i = 0; i < 2; ++i) {
    const int row = min(i * 16 + l15, 21);
    const unsigned short* qp = Qb + (rowbase + row) * 512 + hoff;
#pragma unroll
    for (int kt = 0; kt < 4; ++kt)
      qa[i][kt] = *(const bf16x8*)(qp + kt * 32 + lhi * 8);
  }

  f32x4 acc[2][2] = {};
#pragma unroll
  for (int kt = 0; kt < 4; ++kt) {
    const int klo = kt * 32 + lhi * 8;
    bf16x8 kb[2];
#pragma unroll
    for (int j = 0; j < 2; ++j) {
      const int key = min(j * 16 + l15, 22);
      const unsigned short* kp = (key == 0) ? (kts + b * 512) : (Kb + (rowbase + key - 1) * 512);
      kb[j] = *(const bf16x8*)(kp + hoff + klo);
    }
#pragma unroll
    for (int i = 0; i < 2; ++i)
#pragma unroll
      for (int j = 0; j < 2; ++j)
        acc[i][j] = __builtin_amdgcn_mfma_f32_16x16x32_bf16(qa[i][kt], kb[j], acc[i][j], 0, 0, 0);
  }

  float rinv[2][4];
#pragma unroll
  for (int i = 0; i < 2; ++i)
#pragma unroll
    for (int q = 0; q < 4; ++q) {
      float m = -1e30f;
#pragma unroll
      for (int j = 0; j < 2; ++j)
        if (j * 16 + l15 <= 22) m = fmaxf(m, acc[i][j][q]);
#pragma unroll
      for (int mk = 1; mk < 16; mk <<= 1) m = fmaxf(m, __shfl_xor(m, mk, 64));
      float s = 0.f;
#pragma unroll
      for (int j = 0; j < 2; ++j) {
        const float e = (j * 16 + l15 <= 22) ? __expf(acc[i][j][q] - m) : 0.f;
        acc[i][j][q] = e; s += e;
      }
#pragma unroll
      for (int mk = 1; mk < 16; mk <<= 1) s += __shfl_xor(s, mk, 64);
      rinv[i][q] = 1.f / s;
    }

#pragma unroll
  for (int i = 0; i < 2; ++i)
#pragma unroll
    for (int j = 0; j < 2; ++j)
#pragma unroll
      for (int q = 0; q < 4; ++q)
        Ps[h][i * 16 + lhi * 4 + q][j * 16 + l15] = f2b(acc[i][j][q]);

  __syncthreads();

  f32x4 oac[2][8] = {};
  {
    const int klo = lhi * 8;
    bf16x8 pa[2];
#pragma unroll
    for (int i = 0; i < 2; ++i) pa[i] = *(const bf16x8*)&Ps[h][i * 16 + l15][klo];
#pragma unroll
    for (int jd = 0; jd < 8; ++jd) {
      const bf16x8 vb = *(const bf16x8*)&Vt[h][jd * 16 + l15][klo];
#pragma unroll
      for (int i = 0; i < 2; ++i)
        oac[i][jd] = __builtin_amdgcn_mfma_f32_16x16x32_bf16(pa[i], vb, oac[i][jd], 0, 0, 0);
    }
  }

#pragma unroll
  for (int i = 0; i < 2; ++i)
#pragma unroll
    for (int q = 0; q < 4; ++q) {
      const int r = i * 16 + lhi * 4 + q;
      if (r < 22) {
        const float sc = rinv[i][q];
#pragma unroll
        for (int jd = 0; jd < 8; ++jd)
          Ob[(rowbase + r) * 512 + hoff + jd * 16 + l15] = f2b(oac[i][jd][q] * sc);
      }
    }
}

// ---------------------------------------------------------------------------
// Row norm (ddof=1, eps on sd), f32 input — fallback path.
__global__ __launch_bounds__(256)
void norm_k(const float* __restrict__ in, float* __restrict__ out,
            unsigned short* __restrict__ outB,
            const float* __restrict__ ga, const float* __restrict__ gb, const int mode) {
  const int r = blockIdx.x * 4 + (threadIdx.x >> 6);
  const int lane = threadIdx.x & 63;
  const float* row = in + (size_t)r * 512;
  const float4 v0 = *(const float4*)&row[lane * 4];
  const float4 v1 = *(const float4*)&row[256 + lane * 4];
  float s = v0.x + v0.y + v0.z + v0.w + v1.x + v1.y + v1.z + v1.w;
  float ss = v0.x * v0.x + v0.y * v0.y + v0.z * v0.z + v0.w * v0.w
           + v1.x * v1.x + v1.y * v1.y + v1.z * v1.z + v1.w * v1.w;
#pragma unroll
  for (int m = 1; m < 64; m <<= 1) { s += __shfl_xor(s, m, 64); ss += __shfl_xor(ss, m, 64); }
  const float mean = s * (1.f / 512.f);
  const float var = (ss - 512.f * mean * mean) * (1.f / 511.f);
  const float inv = 1.f / (sqrtf(fmaxf(var, 0.f)) + 1e-6f);
  int ro;
  if (mode == 0) ro = r;
  else if (mode == 1) {
    const int f = r / (B_DIM * J_DIM);
    const int bb = (r / J_DIM) % B_DIM;
    const int j = r % J_DIM;
    ro = (j * B_DIM + bb) * F_DIM + f;
  } else {
    const int j = r / (B_DIM * F_DIM);
    const int bb = (r / F_DIM) % B_DIM;
    const int f = r % F_DIM;
    ro = (f * B_DIM + bb) * J_DIM + j;
  }
  const float4 g0 = *(const float4*)&ga[lane * 4];
  const float4 g1 = *(const float4*)&ga[256 + lane * 4];
  const float4 h0 = *(const float4*)&gb[lane * 4];
  const float4 h1 = *(const float4*)&gb[256 + lane * 4];
  float4 y0, y1;
  y0.x = g0.x * (v0.x - mean) * inv + h0.x;
  y0.y = g0.y * (v0.y - mean) * inv + h0.y;
  y0.z = g0.z * (v0.z - mean) * inv + h0.z;
  y0.w = g0.w * (v0.w - mean) * inv + h0.w;
  y1.x = g1.x * (v1.x - mean) * inv + h1.x;
  y1.y = g1.y * (v1.y - mean) * inv + h1.y;
  y1.z = g1.z * (v1.z - mean) * inv + h1.z;
  y1.w = g1.w * (v1.w - mean) * inv + h1.w;
  if (out) {
    float* orow = out + (size_t)ro * 512;
    *(float4*)&orow[lane * 4] = y0;
    *(float4*)&orow[256 + lane * 4] = y1;
  }
  if (outB) {
    us4 a, b;
    a.x = f2b(y0.x); a.y = f2b(y0.y); a.z = f2b(y0.z); a.w = f2b(y0.w);
    b.x = f2b(y1.x); b.y = f2b(y1.y); b.z = f2b(y1.z); b.w = f2b(y1.w);
    *(us4*)&outB[(size_t)ro * 512 + lane * 4] = a;
    *(us4*)&outB[(size_t)ro * 512 + 256 + lane * 4] = b;
  }
}

// ---------------------------------------------------------------------------
// Row norm, bf16 input (one us8/lane). Optional f32 out and/or bf16 out.
__global__ __launch_bounds__(256)
void normb_k(const unsigned short* __restrict__ in, float* __restrict__ out,
             unsigned short* __restrict__ outB,
             const float* __restrict__ ga, const float* __restrict__ gb, const int mode) {
  const int r = blockIdx.x * 4 + (threadIdx.x >> 6);
  const int lane = threadIdx.x & 63;
  const us8 wv = *(const us8*)&in[(size_t)r * 512 + lane * 8];
  float v[8];
  float s = 0.f, ss = 0.f;
#pragma unroll
  for (int e = 0; e < 8; ++e) {
    v[e] = b2f((unsigned short)wv[e]);
    s += v[e]; ss += v[e] * v[e];
  }
#pragma unroll
  for (int m = 1; m < 64; m <<= 1) { s += __shfl_xor(s, m, 64); ss += __shfl_xor(ss, m, 64); }
  const float mean = s * (1.f / 512.f);
  const float var = (ss - 512.f * mean * mean) * (1.f / 511.f);
  const float inv = 1.f / (sqrtf(fmaxf(var, 0.f)) + 1e-6f);
  int ro;
  if (mode == 0) ro = r;
  else if (mode == 1) {
    const int f = r / (B_DIM * J_DIM);
    const int bb = (r / J_DIM) % B_DIM;
    const int j = r % J_DIM;
    ro = (j * B_DIM + bb) * F_DIM + f;
  } else {
    const int j = r / (B_DIM * F_DIM);
    const int bb = (r / F_DIM) % B_DIM;
    const int f = r % F_DIM;
    ro = (f * B_DIM + bb) * J_DIM + j;
  }
  const float4 g0 = *(const float4*)&ga[lane * 8];
  const float4 g1 = *(const float4*)&ga[lane * 8 + 4];
  const float4 h0 = *(const float4*)&gb[lane * 8];
  const float4 h1 = *(const float4*)&gb[lane * 8 + 4];
  float y[8];
  y[0] = g0.x * (v[0] - mean) * inv + h0.x;
  y[1] = g0.y * (v[1] - mean) * inv + h0.y;
  y[2] = g0.z * (v[2] - mean) * inv + h0.z;
  y[3] = g0.w * (v[3] - mean) * inv + h0.w;
  y[4] = g1.x * (v[4] - mean) * inv + h1.x;
  y[5] = g1.y * (v[5] - mean) * inv + h1.y;
  y[6] = g1.z * (v[6] - mean) * inv + h1.z;
  y[7] = g1.w * (v[7] - mean) * inv + h1.w;
  if (out) {
    float* orow = out + (size_t)ro * 512 + lane * 8;
    __builtin_nontemporal_store(*(f32x4*)&y[0], (f32x4*)&orow[0]);
    __builtin_nontemporal_store(*(f32x4*)&y[4], (f32x4*)&orow[4]);
  }
  if (outB) {
    us8 o;
#pragma unroll
    for (int e = 0; e < 8; ++e) o[e] = f2b(y[e]);
    __builtin_nontemporal_store(o, (us8*)&outB[(size_t)ro * 512 + lane * 8]);
  }
}

// ---------------------------------------------------------------------------
extern "C" void kernel_launch(void* const* d_in, const int* in_sizes, int n_in,
                              void* d_out, int out_size, void* d_ws, size_t ws_size,
                              hipStream_t stream) {
  const float* x   = (const float*)d_in[0];
  const float* tse = (const float*)d_in[1];
  const float* sWq = (const float*)d_in[5];  const float* sbq = (const float*)d_in[6];
  const float* sWk = (const float*)d_in[7];  const float* sbk = (const float*)d_in[8];
  const float* sWv = (const float*)d_in[9];  const float* sbv = (const float*)d_in[10];
  const float* sWo = (const float*)d_in[11]; const float* sbo = (const float*)d_in[12];
  const float* tWq = (const float*)d_in[13]; const float* tbq = (const float*)d_in[14];
  const float* tWk = (const float*)d_in[15]; const float* tbk = (const float*)d_in[16];
  const float* tWv = (const float*)d_in[17]; const float* tbv = (const float*)d_in[18];
  const float* tWo = (const float*)d_in[19]; const float* tbo = (const float*)d_in[20];
  const float* ffW1 = (const float*)d_in[21]; const float* ffb1 = (const float*)d_in[22];
  const float* ffW2 = (const float*)d_in[23]; const float* ffb2 = (const float*)d_in[24];
  const float* n1a = (const float*)d_in[25]; const float* n1b = (const float*)d_in[26];
  const float* n2a = (const float*)d_in[27]; const float* n2b = (const float*)d_in[28];
  const float* n3a = (const float*)d_in[29]; const float* n3b = (const float*)d_in[30];

  char* p = (char*)d_ws;
  auto carve = [&](size_t bytes) { void* r = (void*)p; p += (bytes + 255) & ~(size_t)255; return r; };

  unsigned short* sQKVt = (unsigned short*)carve((size_t)3 * 512 * 512 * 2);
  unsigned short* sOT   = (unsigned short*)carve((size_t)512 * 512 * 2);
  unsigned short* tQKVt = (unsigned short*)carve((size_t)3 * 512 * 512 * 2);
  unsigned short* tOT   = (unsigned short*)carve((size_t)512 * 512 * 2);
  unsigned short* W1T   = (unsigned short*)carve((size_t)2048 * 512 * 2);
  unsigned short* W2T   = (unsigned short*)carve((size_t)512 * 2048 * 2);
  unsigned short* ktss  = (unsigned short*)carve((size_t)64 * 512 * 2);
  unsigned short* vtss  = (unsigned short*)carve((size_t)64 * 512 * 2);
  unsigned short* ktst  = (unsigned short*)carve((size_t)64 * 512 * 2);
  unsigned short* vtst  = (unsigned short*)carve((size_t)64 * 512 * 2);
  unsigned short* Qb    = (unsigned short*)carve((size_t)M_TOK * 512 * 2);

  unsigned short* Kb = (unsigned short*)d_out;   // K/V bf16 + z1/z2 bf16 alias d_out
  unsigned short* Vb = Kb + (size_t)M_TOK * 512;
  float* outF = (float*)d_out;

  const bool bigws = ws_size >= (size_t)873725952ull;
  float* Rbuf = nullptr;
  unsigned short* Hb  = nullptr;   // [M][2048] bf16 FF hidden; early life: xb | rb1
  unsigned short* xb  = nullptr;
  unsigned short* rb1 = nullptr;
  if (bigws) {
    Hb = (unsigned short*)carve((size_t)M_TOK * 2048 * 2);
    xb = Hb;
    rb1 = Hb + (size_t)M_TOK * 512;
  } else {
    Rbuf = (float*)carve((size_t)M_TOK * 512 * 4);
  }

  const float QSCALE = 0.08838834764831845f; // 1/sqrt(128)

  {
    dim3 tb(32, 8);
    Tc8Args tc;
    tc.W[0] = sWq; tc.WT[0] = sQKVt;
    tc.W[1] = sWk; tc.WT[1] = sQKVt + 262144;
    tc.W[2] = sWv; tc.WT[2] = sQKVt + 524288;
    tc.W[3] = sWo; tc.WT[3] = sOT;
    tc.W[4] = tWq; tc.WT[4] = tQKVt;
    tc.W[5] = tWk; tc.WT[5] = tQKVt + 262144;
    tc.W[6] = tWv; tc.WT[6] = tQKVt + 524288;
    tc.W[7] = tWo; tc.WT[7] = tOT;
    tcast8_k<<<dim3(16, 16, 8), tb, 0, stream>>>(tc);
    tcast_k<<<dim3(64, 16), tb, 0, stream>>>(ffW1, W1T, 512, 2048);
    tcast_k<<<dim3(16, 64), tb, 0, stream>>>(ffW2, W2T, 2048, 512);
  }
  {
    TsArgs ta;
    ta.W[0] = sWk; ta.bias[0] = sbk; ta.out[0] = ktss;
    ta.W[1] = sWv; ta.bias[1] = sbv; ta.out[1] = vtss;
    ta.W[2] = tWk; ta.bias[2] = tbk; ta.out[2] = ktst;
    ta.W[3] = tWv; ta.bias[3] = tbv; ta.out[3] = vtst;
    tsproj_k<<<dim3(B_DIM, 2, 4), 1024, 0, stream>>>(tse, ta);
  }

  const int MT = M_TOK / 128;   // 1320 (fallback grids)
  const int MT2 = M_TOK / 256;  // 660  (256-row tiles; all grids %8==0)

  if (bigws) {
    // ---- spatial attention ----
    cast_k<<<2048, 256, 0, stream>>>(x, xb, M_TOK * 512 / 8);
    gemm256_k<EPI_QKV><<<12 * MT2, 512, 0, stream>>>(
        xb, sQKVt, sbq, sbk, sbv, nullptr, nullptr, Qb, Kb, Vb, 512, 512, 512, 512, 12, QSCALE);
    attn_s_k<<<dim3(F_DIM * B_DIM), 256, 0, stream>>>(Qb, Kb, Vb, ktss, vtss, Qb);
    // z1 = attnO@sWo + sbo + xb -> bf16 into Kb (K dead after attn_s; xb live)
    gemm256_k<EPI_RBB><<<4 * MT2, 512, 0, stream>>>(
        Qb, sOT, sbo, nullptr, nullptr, xb, nullptr, Kb, nullptr, nullptr, 512, 512, 512, 512, 4, 1.f);
    normb_k<<<M_TOK / 4, 256, 0, stream>>>(Kb, nullptr, rb1, n1a, n1b, 1);

    // ---- temporal attention ----
    gemm256_k<EPI_QKV><<<12 * MT2, 512, 0, stream>>>(
        rb1, tQKVt, tbq, tbk, tbv, nullptr, nullptr, Qb, Kb, Vb, 512, 512, 512, 512, 12, QSCALE);
    attn_t_k<<<dim3(J_DIM * B_DIM * H_DIM), 256, 0, stream>>>(Qb, Kb, Vb, ktst, vtst, Qb);
    // z2 = attnO@tWo + tbo + rb1 -> bf16 into Kb (K dead after attn_t)
    gemm256_k<EPI_RBB><<<4 * MT2, 512, 0, stream>>>(
        Qb, tOT, tbo, nullptr, nullptr, rb1, nullptr, Kb, nullptr, nullptr, 512, 512, 512, 512, 4, 1.f);
    normb_k<<<M_TOK / 4, 256, 0, stream>>>(Kb, nullptr, Qb, n2a, n2b, 2);

    // ---- feed-forward: gelu + K=2048 proj; z3 in-place in Qb ----
    gemm256_k<EPI_GELU><<<16 * MT2, 512, 0, stream>>>(
        Qb, W1T, ffb1, nullptr, nullptr, nullptr, nullptr, Hb, nullptr, nullptr,
        512, 512, 2048, 512, 16, 1.f);
    gemm256_k<EPI_RBB><<<4 * MT2, 512, 0, stream>>>(
        Hb, W2T, ffb2, nullptr, nullptr, Qb, nullptr, Qb, nullptr, nullptr,
        2048, 2048, 512, 2048, 4, 1.f);
    normb_k<<<M_TOK / 4, 256, 0, stream>>>(Qb, outF, nullptr, n3a, n3b, 0);
  } else {
    // ---- small-ws fallback (round-6 flow, f32 z-chain) ----
    gemmf_k<EPI_QKV><<<12 * MT, 256, 0, stream>>>(
        x, sQKVt, sbq, sbk, sbv, nullptr, nullptr, Qb, Kb, Vb, 512, 512, 512, 512, 12, QSCALE);
    attn_s_k<<<dim3(F_DIM * B_DIM), 256, 0, stream>>>(Qb, Kb, Vb, ktss, vtss, Qb);
    gemm_k<EPI_RES><<<4 * MT, 256, 0, stream>>>(
        Qb, sOT, sbo, nullptr, nullptr, x, outF, nullptr, nullptr, nullptr, 512, 512, 512, 512, 4, 1.f);
    norm_k<<<M_TOK / 4, 256, 0, stream>>>(outF, Rbuf, nullptr, n1a, n1b, 1);

    gemmf_k<EPI_QKV><<<12 * MT, 256, 0, stream>>>(
        Rbuf, tQKVt, tbq, tbk, tbv, nullptr, nullptr, Qb, Kb, Vb, 512, 512, 512, 512, 12, QSCALE);
    attn_t_k<<<dim3(J_DIM * B_DIM * H_DIM), 256, 0, stream>>>(Qb, Kb, Vb, ktst, vtst, Qb);
    gemm_k<EPI_RES><<<4 * MT, 256, 0, stream>>>(
        Qb, tOT, tbo, nullptr, nullptr, Rbuf, outF, nullptr, nullptr, nullptr, 512, 512, 512, 512, 4, 1.f);
    norm_k<<<M_TOK / 4, 256, 0, stream>>>(outF, Rbuf, Qb, n2a, n2b, 2);

    for (int c = 0; c < 4; ++c) {
      gemm_k<EPI_GELU><<<4 * MT, 256, 0, stream>>>(
          Qb, W1T + (size_t)c * 512 * 512, ffb1 + c * 512, nullptr, nullptr,
          nullptr, nullptr, Qb, nullptr, nullptr, 512, 512, 512, 512, 4, 1.f);
      if (c == 0)
        gemm_k<EPI_RES><<<4 * MT, 256, 0, stream>>>(
            Qb, W2T + c * 512, ffb2, nullptr, nullptr, Rbuf, outF,
            nullptr, nullptr, nullptr, 512, 2048, 512, 512, 4, 1.f);
      else
        gemm_k<EPI_ACC><<<4 * MT, 256, 0, stream>>>(
            Qb, W2T + c * 512, nullptr, nullptr, nullptr, nullptr, outF,
            nullptr, nullptr, nullptr, 512, 2048, 512, 512, 4, 1.f);
    }
    norm_k<<<M_TOK / 4, 256, 0, stream>>>(outF, outF, nullptr, n3a, n3b, 0);
  }
}

// Round 15
// 2722.010 us; speedup vs baseline: 1.3132x; 1.0955x over previous
//
#include <hip/hip_runtime.h>
#include <hip/hip_bf16.h>
#include <math.h>

// TransformerDecoder2dLayer on MI355X (gfx950).
// Round 15: single-phase staged epilogue — As/Bs unified into one SMEM block
// so post-loop scratch holds the FULL 256x128 bf16 tile; all 8 waves write
// concurrently (r14 ran two serialized half-phases with half the waves idle),
// one __syncthreads, one us8-nt stream pass. Rest identical to round 14.

#define F_DIM 120
#define B_DIM 64
#define J_DIM 22
#define H_DIM 4
#define M_TOK (F_DIM * B_DIM * J_DIM) // 168960

#define DEV static __device__ __forceinline__

typedef short bf16x8 __attribute__((ext_vector_type(8)));
typedef short us8 __attribute__((ext_vector_type(8)));
typedef float f32x4 __attribute__((ext_vector_type(4)));

struct __align__(8) us4 { unsigned short x, y, z, w; };

DEV unsigned short f2b(float f) {
  unsigned u = __float_as_uint(f);
  u += 0x7fffu + ((u >> 16) & 1u);
  return (unsigned short)(u >> 16);
}
DEV float b2f(unsigned short u) { return __uint_as_float(((unsigned)u) << 16); }

#define GLOAD16(g, l)                                                          \
  __builtin_amdgcn_global_load_lds(                                            \
      (const __attribute__((address_space(1))) void*)(g),                      \
      (__attribute__((address_space(3))) void*)(l), 16, 0, 0)

enum { EPI_QKV = 0, EPI_GELU = 1, EPI_RES = 2, EPI_ACC = 3, EPI_RESB = 4,
       EPI_ROB = 5, EPI_RBB = 6 };

// ---------------------------------------------------------------------------
__global__ __launch_bounds__(256)
void cast_k(const float* __restrict__ in, unsigned short* __restrict__ out, int n8) {
  for (int i = blockIdx.x * 256 + threadIdx.x; i < n8; i += gridDim.x * 256) {
    const float4 a = ((const float4*)in)[i * 2];
    const float4 b = ((const float4*)in)[i * 2 + 1];
    us8 v;
    v[0] = f2b(a.x); v[1] = f2b(a.y); v[2] = f2b(a.z); v[3] = f2b(a.w);
    v[4] = f2b(b.x); v[5] = f2b(b.y); v[6] = f2b(b.z); v[7] = f2b(b.w);
    __builtin_nontemporal_store(v, (us8*)&out[i * 8]);
  }
}

// ---------------------------------------------------------------------------
__global__ __launch_bounds__(256)
void tcast_k(const float* __restrict__ W, unsigned short* __restrict__ WT, int K, int N) {
  __shared__ float t[32][33];
  const int n0 = blockIdx.x * 32, k0 = blockIdx.y * 32;
  const int tx = threadIdx.x, ty = threadIdx.y;
#pragma unroll
  for (int i = 0; i < 4; ++i)
    t[ty + i * 8][tx] = W[(size_t)(k0 + ty + i * 8) * N + n0 + tx];
  __syncthreads();
#pragma unroll
  for (int i = 0; i < 4; ++i)
    WT[(size_t)(n0 + ty + i * 8) * K + k0 + tx] = f2b(t[tx][ty + i * 8]);
}

struct Tc8Args { const float* W[8]; unsigned short* WT[8]; };
__global__ __launch_bounds__(256)
void tcast8_k(Tc8Args a) {
  __shared__ float t[32][33];
  const float* W = a.W[blockIdx.z];
  unsigned short* WT = a.WT[blockIdx.z];
  const int n0 = blockIdx.x * 32, k0 = blockIdx.y * 32;
  const int tx = threadIdx.x, ty = threadIdx.y;
#pragma unroll
  for (int i = 0; i < 4; ++i)
    t[ty + i * 8][tx] = W[(size_t)(k0 + ty + i * 8) * 512 + n0 + tx];
  __syncthreads();
#pragma unroll
  for (int i = 0; i < 4; ++i)
    WT[(size_t)(n0 + ty + i * 8) * 512 + k0 + tx] = f2b(t[tx][ty + i * 8]);
}

// ---------------------------------------------------------------------------
struct TsArgs { const float* W[4]; const float* bias[4]; unsigned short* out[4]; };
__global__ __launch_bounds__(1024)
void tsproj_k(const float* __restrict__ ts, TsArgs a) {
  __shared__ float tsr[512];
  __shared__ float red[3][256];
  const int b = blockIdx.x;
  const int nb = blockIdx.y;
  const int pj = blockIdx.z;
  const int t = threadIdx.x;
  const int n = nb * 256 + (t & 255);
  const int kh = t >> 8;
  if (t < 512) tsr[t] = ts[b * 512 + t];
  __syncthreads();
  const float* W = a.W[pj];
  float acc = 0.f;
  const int k0 = kh * 128;
  for (int k = k0; k < k0 + 128; ++k)
    acc += tsr[k] * W[(size_t)k * 512 + n];
  if (kh) red[kh - 1][t & 255] = acc;
  __syncthreads();
  if (kh == 0) {
    acc += red[0][t & 255] + red[1][t & 255] + red[2][t & 255];
    a.out[pj][b * 512 + n] = f2b(acc + a.bias[pj][n]);
  }
}

// ---------------------------------------------------------------------------
// Scalar epilogue op — fallback kernels only.
template<int EPI>
DEV void epi_store(float v, int row, int col, const float* b0, const float* b1,
                   const float* b2, const void* res, float* outF,
                   unsigned short* o0, unsigned short* o1, unsigned short* o2,
                   int ldo, float scale) {
  if constexpr (EPI == EPI_QKV) {
    const int seg = col >> 9;
    const int cl = col & 511;
    const float* bs = (seg == 0) ? b0 : (seg == 1) ? b1 : b2;
    unsigned short* ob = (seg == 0) ? o0 : (seg == 1) ? o1 : o2;
    const float sc = (seg == 0) ? scale : 1.f;
    v = (v + bs[cl]) * sc;
    ob[(size_t)row * 512 + cl] = f2b(v);
  } else if constexpr (EPI == EPI_GELU) {
    v += b0[col];
    const float a2 = 1.5957691216057308f * (v + 0.044715f * v * v * v);
    const float g = v / (1.f + __expf(-a2));
    o0[(size_t)row * ldo + col] = f2b(g);
  } else if constexpr (EPI == EPI_RES) {
    const size_t off = (size_t)row * 512 + col;
    outF[off] = v + b0[col] + ((const float*)res)[off];
  } else if constexpr (EPI == EPI_RESB) {
    const size_t off = (size_t)row * 512 + col;
    outF[off] = v + b0[col] + b2f(((const unsigned short*)res)[off]);
  } else if constexpr (EPI == EPI_ROB) {
    const size_t off = (size_t)row * 512 + col;
    o0[off] = f2b(v + b0[col] + ((const float*)res)[off]);
  } else if constexpr (EPI == EPI_RBB) {
    const size_t off = (size_t)row * 512 + col;
    o0[off] = f2b(v + b0[col] + b2f(((const unsigned short*)res)[off]));
  } else { // EPI_ACC
    const size_t off = (size_t)row * 512 + col;
    outF[off] = v + outF[off];
  }
}

// ---------------------------------------------------------------------------
// 256x128 GEMM, BK=32, 8 waves (4m x 2n) of 64x64; triple-buffered LDS in a
// unified SMEM block, counted vmcnt(3), 1 s_barrier/step. Epilogue
// (QKV/GELU/RBB): all 8 waves write the full 256x128 bf16 tile into SMEM
// (granule-XOR swizzle) concurrently, one __syncthreads, one us8-nt stream.
template<int EPI>
__global__ __launch_bounds__(512, 4)
void gemm256_k(const unsigned short* __restrict__ Ab, const unsigned short* __restrict__ Wt,
               const float* __restrict__ b0, const float* __restrict__ b1, const float* __restrict__ b2,
               const void* __restrict__ res, float* __restrict__ outF,
               unsigned short* __restrict__ o0, unsigned short* __restrict__ o1, unsigned short* __restrict__ o2,
               int lda, int ldw, int ldo, int nk, int nx, float scale) {
  __shared__ unsigned short SMEM[36864];   // 72KB: A 3x8192 | B 3x4096 ; Ot post-loop
  const int tid = threadIdx.x;
  const int chunkg = gridDim.x >> 3;       // XCD-chunked bijective swizzle (nwg%8==0)
  const int wg = (blockIdx.x & 7) * chunkg + (blockIdx.x >> 3);
  const int nbase = (wg % nx) * 128;
  const int mbase = (wg / nx) * 256;
  const int lane = tid & 63;
  const int w = tid >> 6;
  const int wr = (w >> 1) * 64;
  const int wc = (w & 1) * 64;
  const int l15 = lane & 15;
  const int lhi = lane >> 4;

  const int crow = lane >> 2;
  const int ccol = (((lane & 3) ^ ((lane >> 3) & 3)) << 3);
  const unsigned short* gA0 = Ab + (size_t)(mbase + 32 * w + crow) * lda + ccol;
  const unsigned short* gA1 = gA0 + (size_t)16 * lda;
  const unsigned short* gB0 = Wt + (size_t)(nbase + 16 * w + crow) * ldw + ccol;

  auto Asb = [&](int bb) { return &SMEM[bb * 8192]; };
  auto Bsb = [&](int bb) { return &SMEM[24576 + bb * 4096]; };

  auto stage = [&](int bb, int kt) {   // 3 vmem ops / wave
    GLOAD16(gA0 + kt, &Asb(bb)[(2 * w) * 512]);
    GLOAD16(gA1 + kt, &Asb(bb)[(2 * w + 1) * 512]);
    GLOAD16(gB0 + kt, &Bsb(bb)[w * 512]);
  };

  f32x4 acc[4][4] = {};
  const int KT = nk >> 5;
  const int swz = ((lhi ^ ((l15 >> 1) & 3)) << 3);

  stage(0, 0);
  stage(1, 32);
  asm volatile("s_waitcnt vmcnt(3)" ::: "memory");
  __builtin_amdgcn_s_barrier();

  for (int t = 0; t < KT; ++t) {
    const unsigned short* as = Asb(t % 3);
    const unsigned short* bs = Bsb(t % 3);
    if (t + 2 < KT) stage((t + 2) % 3, (t + 2) << 5);
    bf16x8 afr[4], bfr[4];
#pragma unroll
    for (int i = 0; i < 4; ++i) afr[i] = *(const bf16x8*)&as[(wr + i * 16 + l15) * 32 + swz];
#pragma unroll
    for (int j = 0; j < 4; ++j) bfr[j] = *(const bf16x8*)&bs[(wc + j * 16 + l15) * 32 + swz];
#pragma unroll
    for (int i = 0; i < 4; ++i)
#pragma unroll
      for (int j = 0; j < 4; ++j)
        acc[i][j] = __builtin_amdgcn_mfma_f32_16x16x32_bf16(afr[i], bfr[j], acc[i][j], 0, 0, 0);
    if (t + 2 < KT)      asm volatile("s_waitcnt vmcnt(3) lgkmcnt(0)" ::: "memory");
    else if (t + 1 < KT) asm volatile("s_waitcnt vmcnt(0) lgkmcnt(0)" ::: "memory");
    else                 asm volatile("s_waitcnt lgkmcnt(0)" ::: "memory");
    __builtin_amdgcn_s_barrier();
  }

  if constexpr (EPI == EPI_QKV || EPI == EPI_GELU || EPI == EPI_RBB) {
    // ---- single-phase staged vectorized epilogue ----
    unsigned short* Ot = &SMEM[0];   // 36864 shorts free; full tile needs 32768
    const int seg = (EPI == EPI_QKV) ? (nbase >> 9) : 0;   // tile fits one segment
    unsigned short* ob = (EPI == EPI_QKV) ? ((seg == 0) ? o0 : (seg == 1) ? o1 : o2) : o0;
    const float* bb = (EPI == EPI_QKV) ? ((seg == 0) ? b0 : (seg == 1) ? b1 : b2) : b0;
    const float sc = (EPI == EPI_QKV && 0 == seg) ? scale : 1.f;
    const int cb = (EPI == EPI_QKV) ? (nbase & 511) : nbase;
    // write phase: all 8 waves, disjoint quadrants of the 256x128 tile
#pragma unroll
    for (int i = 0; i < 4; ++i)
#pragma unroll
      for (int j = 0; j < 4; ++j) {
        const int c = wc + j * 16 + l15;
#pragma unroll
        for (int q = 0; q < 4; ++q) {
          const int row = wr + i * 16 + (lhi << 2) + q;
          float v = acc[i][j][q];
          if constexpr (EPI == EPI_QKV) {
            v = (v + bb[cb + c]) * sc;
          } else if constexpr (EPI == EPI_GELU) {
            v += bb[cb + c];
            const float a2 = 1.5957691216057308f * (v + 0.044715f * v * v * v);
            v = v / (1.f + __expf(-a2));
          } else {  // RBB: bias now, residual in stream phase
            v += bb[cb + c];
          }
          Ot[(row << 7) + ((((c >> 3) ^ (row & 7)) << 3) | (c & 7))] = f2b(v);
        }
      }
    __syncthreads();   // full fence: ds_writes visible to all threads
#pragma unroll
    for (int ps = 0; ps < 8; ++ps) {   // 8 x 512 thr x 16B = 64KB full tile
      const int idx = (ps * 512 + tid) * 8;
      const int row = idx >> 7;
      const int c = idx & 127;
      us8 val = *(const us8*)&Ot[(row << 7) + (((c >> 3) ^ (row & 7)) << 3)];
      const size_t grow = (size_t)(mbase + row);
      const int gcol = cb + c;
      if constexpr (EPI == EPI_RBB) {
        const us8 r = __builtin_nontemporal_load(
            (const us8*)&((const unsigned short*)res)[grow * 512 + gcol]);
#pragma unroll
        for (int e = 0; e < 8; ++e)
          val[e] = (short)f2b(b2f((unsigned short)val[e]) + b2f((unsigned short)r[e]));
      }
      __builtin_nontemporal_store(val, (us8*)&ob[grow * ldo + gcol]);
    }
  } else {
#pragma unroll
    for (int i = 0; i < 4; ++i)
#pragma unroll
      for (int j = 0; j < 4; ++j) {
        const int row0 = mbase + wr + i * 16 + (lhi << 2);
        const int col = nbase + wc + j * 16 + l15;
#pragma unroll
        for (int q = 0; q < 4; ++q)
          epi_store<EPI>(acc[i][j][q], row0 + q, col, b0, b1, b2, res, outF, o0, o1, o2, ldo, scale);
      }
  }
}

// ---------------------------------------------------------------------------
// 128x128 pipelined GEMM — small-ws fallback path.
template<int EPI>
__global__ __launch_bounds__(256)
void gemm_k(const unsigned short* __restrict__ Ab, const unsigned short* __restrict__ Wt,
            const float* __restrict__ b0, const float* __restrict__ b1, const float* __restrict__ b2,
            const void* __restrict__ res, float* __restrict__ outF,
            unsigned short* __restrict__ o0, unsigned short* __restrict__ o1, unsigned short* __restrict__ o2,
            int lda, int ldw, int ldo, int nk, int nx, float scale) {
  __shared__ unsigned short As[3][4096];
  __shared__ unsigned short Bs[3][4096];
  const int tid = threadIdx.x;
  const int chunkg = gridDim.x >> 3;
  const int wg = (blockIdx.x & 7) * chunkg + (blockIdx.x >> 3);
  const int nbase = (wg % nx) * 128;
  const int mbase = (wg / nx) * 128;
  const int lane = tid & 63;
  const int w = tid >> 6;
  const int wr = (w >> 1) * 64;
  const int wc = (w & 1) * 64;
  const int l15 = lane & 15;
  const int lhi = lane >> 4;

  const int crow = lane >> 2;
  const int ccol = (((lane & 3) ^ ((lane >> 3) & 3)) << 3);
  const unsigned short* gA0 = Ab + (size_t)(mbase + 32 * w + crow) * lda + ccol;
  const unsigned short* gA1 = gA0 + (size_t)16 * lda;
  const unsigned short* gB0 = Wt + (size_t)(nbase + 32 * w + crow) * ldw + ccol;
  const unsigned short* gB1 = gB0 + (size_t)16 * ldw;

  auto stage = [&](int bb, int kt) {
    GLOAD16(gA0 + kt, &As[bb][(2 * w) * 512]);
    GLOAD16(gA1 + kt, &As[bb][(2 * w + 1) * 512]);
    GLOAD16(gB0 + kt, &Bs[bb][(2 * w) * 512]);
    GLOAD16(gB1 + kt, &Bs[bb][(2 * w + 1) * 512]);
  };

  f32x4 acc[4][4] = {};
  const int KT = nk >> 5;
  const int swz = ((lhi ^ ((l15 >> 1) & 3)) << 3);

  stage(0, 0);
  stage(1, 32);
  asm volatile("s_waitcnt vmcnt(4)" ::: "memory");
  __builtin_amdgcn_s_barrier();

  for (int t = 0; t < KT; ++t) {
    const unsigned short* as = As[t % 3];
    const unsigned short* bs = Bs[t % 3];
    if (t + 2 < KT) stage((t + 2) % 3, (t + 2) << 5);
    bf16x8 afr[4], bfr[4];
#pragma unroll
    for (int i = 0; i < 4; ++i) afr[i] = *(const bf16x8*)&as[(wr + i * 16 + l15) * 32 + swz];
#pragma unroll
    for (int j = 0; j < 4; ++j) bfr[j] = *(const bf16x8*)&bs[(wc + j * 16 + l15) * 32 + swz];
#pragma unroll
    for (int i = 0; i < 4; ++i)
#pragma unroll
      for (int j = 0; j < 4; ++j)
        acc[i][j] = __builtin_amdgcn_mfma_f32_16x16x32_bf16(afr[i], bfr[j], acc[i][j], 0, 0, 0);
    if (t + 2 < KT)      asm volatile("s_waitcnt vmcnt(4) lgkmcnt(0)" ::: "memory");
    else if (t + 1 < KT) asm volatile("s_waitcnt vmcnt(0) lgkmcnt(0)" ::: "memory");
    else                 asm volatile("s_waitcnt lgkmcnt(0)" ::: "memory");
    __builtin_amdgcn_s_barrier();
  }

#pragma unroll
  for (int i = 0; i < 4; ++i)
#pragma unroll
    for (int j = 0; j < 4; ++j) {
      const int row0 = mbase + wr + i * 16 + (lhi << 2);
      const int col = nbase + wc + j * 16 + l15;
#pragma unroll
      for (int q = 0; q < 4; ++q)
        epi_store<EPI>(acc[i][j][q], row0 + q, col, b0, b1, b2, res, outF, o0, o1, o2, ldo, scale);
    }
}

// ---------------------------------------------------------------------------
// Legacy reg-staging GEMM for f32 A (small-ws fallback only).
template<int EPI>
__global__ __launch_bounds__(256)
void gemmf_k(const float* __restrict__ Af, const unsigned short* __restrict__ Wt,
             const float* __restrict__ b0, const float* __restrict__ b1, const float* __restrict__ b2,
             const void* __restrict__ res, float* __restrict__ outF,
             unsigned short* __restrict__ o0, unsigned short* __restrict__ o1, unsigned short* __restrict__ o2,
             int lda, int ldw, int ldo, int nk, int nx, float scale) {
  __shared__ unsigned short As[128][40];
  __shared__ unsigned short Bs[128][40];
  const int tid = threadIdx.x;
  const int chunkg = gridDim.x >> 3;
  const int wg = (blockIdx.x & 7) * chunkg + (blockIdx.x >> 3);
  const int nbase = (wg % nx) * 128;
  const int mbase = (wg / nx) * 128;
  const int lane = tid & 63;
  const int w = tid >> 6;
  const int wr = (w >> 1) * 64;
  const int wc = (w & 1) * 64;
  const int l15 = lane & 15;
  const int lhi = lane >> 4;

  float4 ra[4];
  us4 rb[4];
  auto loadAB = [&](int kt) {
#pragma unroll
    for (int i = 0; i < 4; ++i) {
      const int g = i * 256 + tid;
      const int r = g >> 3;
      const int c = (g & 7) << 2;
      ra[i] = *(const float4*)(Af + (size_t)(mbase + r) * lda + kt + c);
      rb[i] = *(const us4*)(Wt + (size_t)(nbase + r) * ldw + kt + c);
    }
  };
  auto storeAB = [&]() {
#pragma unroll
    for (int i = 0; i < 4; ++i) {
      const int g = i * 256 + tid;
      const int r = g >> 3;
      const int c = (g & 7) << 2;
      us4 ua;
      ua.x = f2b(ra[i].x); ua.y = f2b(ra[i].y); ua.z = f2b(ra[i].z); ua.w = f2b(ra[i].w);
      *(us4*)&As[r][c] = ua;
      *(us4*)&Bs[r][c] = rb[i];
    }
  };

  f32x4 acc[4][4] = {};
  const int KT = nk >> 5;
  loadAB(0);
  storeAB();
  __syncthreads();
  for (int t = 0; t < KT; ++t) {
    if (t + 1 < KT) loadAB((t + 1) << 5);
    bf16x8 afr[4], bfr[4];
    const int klo = lhi << 3;
#pragma unroll
    for (int i = 0; i < 4; ++i) afr[i] = *(const bf16x8*)&As[wr + i * 16 + l15][klo];
#pragma unroll
    for (int j = 0; j < 4; ++j) bfr[j] = *(const bf16x8*)&Bs[wc + j * 16 + l15][klo];
#pragma unroll
    for (int i = 0; i < 4; ++i)
#pragma unroll
      for (int j = 0; j < 4; ++j)
        acc[i][j] = __builtin_amdgcn_mfma_f32_16x16x32_bf16(afr[i], bfr[j], acc[i][j], 0, 0, 0);
    __syncthreads();
    if (t + 1 < KT) { storeAB(); __syncthreads(); }
  }

#pragma unroll
  for (int i = 0; i < 4; ++i)
#pragma unroll
    for (int j = 0; j < 4; ++j) {
      const int row0 = mbase + wr + i * 16 + (lhi << 2);
      const int col = nbase + wc + j * 16 + l15;
#pragma unroll
      for (int q = 0; q < 4; ++q)
        epi_store<EPI>(acc[i][j][q], row0 + q, col, b0, b1, b2, res, outF, o0, o1, o2, ldo, scale);
    }
}

// ---------------------------------------------------------------------------
// Temporal MFMA attention. Block = (instance, head): 1408*4 blocks, 4 waves.
__global__ __launch_bounds__(256)
void attn_t_k(const unsigned short* __restrict__ Qb, const unsigned short* __restrict__ Kb,
              const unsigned short* __restrict__ Vb, const unsigned short* __restrict__ kts,
              const unsigned short* __restrict__ vts, unsigned short* __restrict__ Ob) {
  __shared__ unsigned short Ps[128][134];
  __shared__ unsigned short Vt[64][134];
  const int tid = threadIdx.x;
  const int inst = blockIdx.x >> 2;
  const int h = blockIdx.x & 3;
  const int b = inst & (B_DIM - 1);
  const size_t rowbase = (size_t)inst * 120;
  const int hoff = h * 128;
  const int lane = tid & 63;
  const int w = tid >> 6;
  const int wr = w * 32;
  const int l15 = lane & 15;
  const int lhi = lane >> 4;

  auto stageV = [&](int half) {
    for (int e = tid; e < 2048; e += 256) {
      const int d4 = (e & 15) << 2;
      const int key = e >> 4;
      us4 v;
      if (key <= 120) {
        const unsigned short* src = (key == 0) ? (vts + b * 512) : (Vb + (rowbase + key - 1) * 512);
        v = *(const us4*)(src + hoff + half * 64 + d4);
      } else { v.x = 0; v.y = 0; v.z = 0; v.w = 0; }
      Vt[d4 + 0][key] = v.x; Vt[d4 + 1][key] = v.y; Vt[d4 + 2][key] = v.z; Vt[d4 + 3][key] = v.w;
    }
  };
  stageV(0);

  bf16x8 qa[2][4];
#pragma unroll
  for (int i = 0; i < 2; ++i) {
    const int row = min(wr + i * 16 + l15, 119);
    const unsigned short* qp = Qb + (rowbase + row) * 512 + hoff;
#pragma unroll
    for (int kt = 0; kt < 4; ++kt)
      qa[i][kt] = *(const bf16x8*)(qp + kt * 32 + lhi * 8);
  }

  f32x4 acc[2][8] = {};
#pragma unroll
  for (int kt = 0; kt < 4; ++kt) {
    const int klo = kt * 32 + lhi * 8;
    bf16x8 kb[8];
#pragma unroll
    for (int j = 0; j < 8; ++j) {
      const int key = min(j * 16 + l15, 120);
      const unsigned short* kp = (key == 0) ? (kts + b * 512) : (Kb + (rowbase + key - 1) * 512);
      kb[j] = *(const bf16x8*)(kp + hoff + klo);
    }
#pragma unroll
    for (int i = 0; i < 2; ++i)
#pragma unroll
      for (int j = 0; j < 8; ++j)
        acc[i][j] = __builtin_amdgcn_mfma_f32_16x16x32_bf16(qa[i][kt], kb[j], acc[i][j], 0, 0, 0);
  }

  float rinv[2][4];
#pragma unroll
  for (int i = 0; i < 2; ++i)
#pragma unroll
    for (int q = 0; q < 4; ++q) {
      float m = -1e30f;
#pragma unroll
      for (int j = 0; j < 8; ++j)
        if (j * 16 + l15 <= 120) m = fmaxf(m, acc[i][j][q]);
#pragma unroll
      for (int mk = 1; mk < 16; mk <<= 1) m = fmaxf(m, __shfl_xor(m, mk, 64));
      float s = 0.f;
#pragma unroll
      for (int j = 0; j < 8; ++j) {
        const float e = (j * 16 + l15 <= 120) ? __expf(acc[i][j][q] - m) : 0.f;
        acc[i][j][q] = e; s += e;
      }
#pragma unroll
      for (int mk = 1; mk < 16; mk <<= 1) s += __shfl_xor(s, mk, 64);
      rinv[i][q] = 1.f / s;
    }

#pragma unroll
  for (int i = 0; i < 2; ++i)
#pragma unroll
    for (int j = 0; j < 8; ++j)
#pragma unroll
      for (int q = 0; q < 4; ++q)
        Ps[wr + i * 16 + lhi * 4 + q][j * 16 + l15] = f2b(acc[i][j][q]);

  __syncthreads();

#pragma unroll
  for (int half = 0; half < 2; ++half) {
    if (half == 1) {
      __syncthreads();
      stageV(1);
      __syncthreads();
    }
    f32x4 oac[2][4] = {};
#pragma unroll
    for (int kt = 0; kt < 4; ++kt) {
      const int klo = kt * 32 + lhi * 8;
      bf16x8 pa[2], vb[4];
#pragma unroll
      for (int i = 0; i < 2; ++i) pa[i] = *(const bf16x8*)&Ps[wr + i * 16 + l15][klo];
#pragma unroll
      for (int jd = 0; jd < 4; ++jd) vb[jd] = *(const bf16x8*)&Vt[jd * 16 + l15][klo];
#pragma unroll
      for (int i = 0; i < 2; ++i)
#pragma unroll
        for (int jd = 0; jd < 4; ++jd)
          oac[i][jd] = __builtin_amdgcn_mfma_f32_16x16x32_bf16(pa[i], vb[jd], oac[i][jd], 0, 0, 0);
    }
#pragma unroll
    for (int i = 0; i < 2; ++i)
#pragma unroll
      for (int q = 0; q < 4; ++q) {
        const int r = wr + i * 16 + lhi * 4 + q;
        if (r < 120) {
          const float sc = rinv[i][q];
#pragma unroll
          for (int jd = 0; jd < 4; ++jd)
            Ob[(rowbase + r) * 512 + hoff + half * 64 + jd * 16 + l15] = f2b(oac[i][jd][q] * sc);
        }
      }
  }
}

// ---------------------------------------------------------------------------
// Spatial MFMA attention. Block = (f,b) instance (7680 blocks), wave = head.
__global__ __launch_bounds__(256)
void attn_s_k(const unsigned short* __restrict__ Qb, const unsigned short* __restrict__ Kb,
              const unsigned short* __restrict__ Vb, const unsigned short* __restrict__ kts,
              const unsigned short* __restrict__ vts, unsigned short* __restrict__ Ob) {
  __shared__ unsigned short Ps[4][32][34];
  __shared__ unsigned short Vt[4][128][34];
  const int tid = threadIdx.x;
  const int inst = blockIdx.x;
  const int b = inst & (B_DIM - 1);
  const size_t rowbase = (size_t)inst * 22;
  const int lane = tid & 63;
  const int h = tid >> 6;
  const int l15 = lane & 15;
  const int lhi = lane >> 4;
  const int hoff = h * 128;

  for (int e = tid; e < 4096; e += 256) {
    const int h2 = e >> 10;
    const int rem = e & 1023;
    const int key = rem >> 5;
    const int d4 = (rem & 31) << 2;
    us4 v;
    if (key <= 22) {
      const unsigned short* src = (key == 0) ? (vts + b * 512) : (Vb + (rowbase + key - 1) * 512);
      v = *(const us4*)(src + h2 * 128 + d4);
    } else { v.x = 0; v.y = 0; v.z = 0; v.w = 0; }
    Vt[h2][d4 + 0][key] = v.x; Vt[h2][d4 + 1][key] = v.y; Vt[h2][d4 + 2][key] = v.z; Vt[h2][d4 + 3][key] = v.w;
  }

  bf16x8 qa[2][4];
#pragma unroll
  for (int i = 0; i < 2; ++i) {
    const int row = min(i * 16 + l15, 21);
    const unsigned short* qp = Qb + (rowbase + row) * 512 + hoff;
#pragma unroll
    for (int kt = 0; kt < 4; ++kt)
      qa[i][kt] = *(const bf16x8*)(qp + kt * 32 + lhi * 8);
  }

  f32x4 acc[2][2] = {};
#pragma unroll
  for (int kt = 0; kt < 4; ++kt) {
    const int klo = kt * 32 + lhi * 8;
    bf16x8 kb[2];
#pragma unroll
    for (int j = 0; j < 2; ++j) {
      const int key = min(j * 16 + l15, 22);
      const unsigned short* kp = (key == 0) ? (kts + b * 512) : (Kb + (rowbase + key - 1) * 512);
      kb[j] = *(const bf16x8*)(kp + hoff + klo);
    }
#pragma unroll
    for (int i = 0; i < 2; ++i)
#pragma unroll
      for (int j = 0; j < 2; ++j)
        acc[i][j] = __builtin_amdgcn_mfma_f32_16x16x32_bf16(qa[i][kt], kb[j], acc[i][j], 0, 0, 0);
  }

  float rinv[2][4];
#pragma unroll
  for (int i = 0; i < 2; ++i)
#pragma unroll
    for (int q = 0; q < 4; ++q) {
      float m = -1e30f;
#pragma unroll
      for (int j = 0; j < 2; ++j)
        if (j * 16 + l15 <= 22) m = fmaxf(m, acc[i][j][q]);
#pragma unroll
      for (int mk = 1; mk < 16; mk <<= 1) m = fmaxf(m, __shfl_xor(m, mk, 64));
      float s = 0.f;
#pragma unroll
      for (int j = 0; j < 2; ++j) {
        const float e = (j * 16 + l15 <= 22) ? __expf(acc[i][j][q] - m) : 0.f;
        acc[i][j][q] = e; s += e;
      }
#pragma unroll
      for (int mk = 1; mk < 16; mk <<= 1) s += __shfl_xor(s, mk, 64);
      rinv[i][q] = 1.f / s;
    }

#pragma unroll
  for (int i = 0; i < 2; ++i)
#pragma unroll
    for (int j = 0; j < 2; ++j)
#pragma unroll
      for (int q = 0; q < 4; ++q)
        Ps[h][i * 16 + lhi * 4 + q][j * 16 + l15] = f2b(acc[i][j][q]);

  __syncthreads();

  f32x4 oac[2][8] = {};
  {
    const int klo = lhi * 8;
    bf16x8 pa[2];
#pragma unroll
    for (int i = 0; i < 2; ++i) pa[i] = *(const bf16x8*)&Ps[h][i * 16 + l15][klo];
#pragma unroll
    for (int jd = 0; jd < 8; ++jd) {
      const bf16x8 vb = *(const bf16x8*)&Vt[h][jd * 16 + l15][klo];
#pragma unroll
      for (int i = 0; i < 2; ++i)
        oac[i][jd] = __builtin_amdgcn_mfma_f32_16x16x32_bf16(pa[i], vb, oac[i][jd], 0, 0, 0);
    }
  }

#pragma unroll
  for (int i = 0; i < 2; ++i)
#pragma unroll
    for (int q = 0; q < 4; ++q) {
      const int r = i * 16 + lhi * 4 + q;
      if (r < 22) {
        const float sc = rinv[i][q];
#pragma unroll
        for (int jd = 0; jd < 8; ++jd)
          Ob[(rowbase + r) * 512 + hoff + jd * 16 + l15] = f2b(oac[i][jd][q] * sc);
      }
    }
}

// ---------------------------------------------------------------------------
// Row norm (ddof=1, eps on sd), f32 input — fallback path.
__global__ __launch_bounds__(256)
void norm_k(const float* __restrict__ in, float* __restrict__ out,
            unsigned short* __restrict__ outB,
            const float* __restrict__ ga, const float* __restrict__ gb, const int mode) {
  const int r = blockIdx.x * 4 + (threadIdx.x >> 6);
  const int lane = threadIdx.x & 63;
  const float* row = in + (size_t)r * 512;
  const float4 v0 = *(const float4*)&row[lane * 4];
  const float4 v1 = *(const float4*)&row[256 + lane * 4];
  float s = v0.x + v0.y + v0.z + v0.w + v1.x + v1.y + v1.z + v1.w;
  float ss = v0.x * v0.x + v0.y * v0.y + v0.z * v0.z + v0.w * v0.w
           + v1.x * v1.x + v1.y * v1.y + v1.z * v1.z + v1.w * v1.w;
#pragma unroll
  for (int m = 1; m < 64; m <<= 1) { s += __shfl_xor(s, m, 64); ss += __shfl_xor(ss, m, 64); }
  const float mean = s * (1.f / 512.f);
  const float var = (ss - 512.f * mean * mean) * (1.f / 511.f);
  const float inv = 1.f / (sqrtf(fmaxf(var, 0.f)) + 1e-6f);
  int ro;
  if (mode == 0) ro = r;
  else if (mode == 1) {
    const int f = r / (B_DIM * J_DIM);
    const int bb = (r / J_DIM) % B_DIM;
    const int j = r % J_DIM;
    ro = (j * B_DIM + bb) * F_DIM + f;
  } else {
    const int j = r / (B_DIM * F_DIM);
    const int bb = (r / F_DIM) % B_DIM;
    const int f = r % F_DIM;
    ro = (f * B_DIM + bb) * J_DIM + j;
  }
  const float4 g0 = *(const float4*)&ga[lane * 4];
  const float4 g1 = *(const float4*)&ga[256 + lane * 4];
  const float4 h0 = *(const float4*)&gb[lane * 4];
  const float4 h1 = *(const float4*)&gb[256 + lane * 4];
  float4 y0, y1;
  y0.x = g0.x * (v0.x - mean) * inv + h0.x;
  y0.y = g0.y * (v0.y - mean) * inv + h0.y;
  y0.z = g0.z * (v0.z - mean) * inv + h0.z;
  y0.w = g0.w * (v0.w - mean) * inv + h0.w;
  y1.x = g1.x * (v1.x - mean) * inv + h1.x;
  y1.y = g1.y * (v1.y - mean) * inv + h1.y;
  y1.z = g1.z * (v1.z - mean) * inv + h1.z;
  y1.w = g1.w * (v1.w - mean) * inv + h1.w;
  if (out) {
    float* orow = out + (size_t)ro * 512;
    *(float4*)&orow[lane * 4] = y0;
    *(float4*)&orow[256 + lane * 4] = y1;
  }
  if (outB) {
    us4 a, b;
    a.x = f2b(y0.x); a.y = f2b(y0.y); a.z = f2b(y0.z); a.w = f2b(y0.w);
    b.x = f2b(y1.x); b.y = f2b(y1.y); b.z = f2b(y1.z); b.w = f2b(y1.w);
    *(us4*)&outB[(size_t)ro * 512 + lane * 4] = a;
    *(us4*)&outB[(size_t)ro * 512 + 256 + lane * 4] = b;
  }
}

// ---------------------------------------------------------------------------
// Row norm, bf16 input (one us8/lane). Optional f32 out and/or bf16 out.
__global__ __launch_bounds__(256)
void normb_k(const unsigned short* __restrict__ in, float* __restrict__ out,
             unsigned short* __restrict__ outB,
             const float* __restrict__ ga, const float* __restrict__ gb, const int mode) {
  const int r = blockIdx.x * 4 + (threadIdx.x >> 6);
  const int lane = threadIdx.x & 63;
  const us8 wv = *(const us8*)&in[(size_t)r * 512 + lane * 8];
  float v[8];
  float s = 0.f, ss = 0.f;
#pragma unroll
  for (int e = 0; e < 8; ++e) {
    v[e] = b2f((unsigned short)wv[e]);
    s += v[e]; ss += v[e] * v[e];
  }
#pragma unroll
  for (int m = 1; m < 64; m <<= 1) { s += __shfl_xor(s, m, 64); ss += __shfl_xor(ss, m, 64); }
  const float mean = s * (1.f / 512.f);
  const float var = (ss - 512.f * mean * mean) * (1.f / 511.f);
  const float inv = 1.f / (sqrtf(fmaxf(var, 0.f)) + 1e-6f);
  int ro;
  if (mode == 0) ro = r;
  else if (mode == 1) {
    const int f = r / (B_DIM * J_DIM);
    const int bb = (r / J_DIM) % B_DIM;
    const int j = r % J_DIM;
    ro = (j * B_DIM + bb) * F_DIM + f;
  } else {
    const int j = r / (B_DIM * F_DIM);
    const int bb = (r / F_DIM) % B_DIM;
    const int f = r % F_DIM;
    ro = (f * B_DIM + bb) * J_DIM + j;
  }
  const float4 g0 = *(const float4*)&ga[lane * 8];
  const float4 g1 = *(const float4*)&ga[lane * 8 + 4];
  const float4 h0 = *(const float4*)&gb[lane * 8];
  const float4 h1 = *(const float4*)&gb[lane * 8 + 4];
  float y[8];
  y[0] = g0.x * (v[0] - mean) * inv + h0.x;
  y[1] = g0.y * (v[1] - mean) * inv + h0.y;
  y[2] = g0.z * (v[2] - mean) * inv + h0.z;
  y[3] = g0.w * (v[3] - mean) * inv + h0.w;
  y[4] = g1.x * (v[4] - mean) * inv + h1.x;
  y[5] = g1.y * (v[5] - mean) * inv + h1.y;
  y[6] = g1.z * (v[6] - mean) * inv + h1.z;
  y[7] = g1.w * (v[7] - mean) * inv + h1.w;
  if (out) {
    float* orow = out + (size_t)ro * 512 + lane * 8;
    __builtin_nontemporal_store(*(f32x4*)&y[0], (f32x4*)&orow[0]);
    __builtin_nontemporal_store(*(f32x4*)&y[4], (f32x4*)&orow[4]);
  }
  if (outB) {
    us8 o;
#pragma unroll
    for (int e = 0; e < 8; ++e) o[e] = f2b(y[e]);
    __builtin_nontemporal_store(o, (us8*)&outB[(size_t)ro * 512 + lane * 8]);
  }
}

// ---------------------------------------------------------------------------
extern "C" void kernel_launch(void* const* d_in, const int* in_sizes, int n_in,
                              void* d_out, int out_size, void* d_ws, size_t ws_size,
                              hipStream_t stream) {
  const float* x   = (const float*)d_in[0];
  const float* tse = (const float*)d_in[1];
  const float* sWq = (const float*)d_in[5];  const float* sbq = (const float*)d_in[6];
  const float* sWk = (const float*)d_in[7];  const float* sbk = (const float*)d_in[8];
  const float* sWv = (const float*)d_in[9];  const float* sbv = (const float*)d_in[10];
  const float* sWo = (const float*)d_in[11]; const float* sbo = (const float*)d_in[12];
  const float* tWq = (const float*)d_in[13]; const float* tbq = (const float*)d_in[14];
  const float* tWk = (const float*)d_in[15]; const float* tbk = (const float*)d_in[16];
  const float* tWv = (const float*)d_in[17]; const float* tbv = (const float*)d_in[18];
  const float* tWo = (const float*)d_in[19]; const float* tbo = (const float*)d_in[20];
  const float* ffW1 = (const float*)d_in[21]; const float* ffb1 = (const float*)d_in[22];
  const float* ffW2 = (const float*)d_in[23]; const float* ffb2 = (const float*)d_in[24];
  const float* n1a = (const float*)d_in[25]; const float* n1b = (const float*)d_in[26];
  const float* n2a = (const float*)d_in[27]; const float* n2b = (const float*)d_in[28];
  const float* n3a = (const float*)d_in[29]; const float* n3b = (const float*)d_in[30];

  char* p = (char*)d_ws;
  auto carve = [&](size_t bytes) { void* r = (void*)p; p += (bytes + 255) & ~(size_t)255; return r; };

  unsigned short* sQKVt = (unsigned short*)carve((size_t)3 * 512 * 512 * 2);
  unsigned short* sOT   = (unsigned short*)carve((size_t)512 * 512 * 2);
  unsigned short* tQKVt = (unsigned short*)carve((size_t)3 * 512 * 512 * 2);
  unsigned short* tOT   = (unsigned short*)carve((size_t)512 * 512 * 2);
  unsigned short* W1T   = (unsigned short*)carve((size_t)2048 * 512 * 2);
  unsigned short* W2T   = (unsigned short*)carve((size_t)512 * 2048 * 2);
  unsigned short* ktss  = (unsigned short*)carve((size_t)64 * 512 * 2);
  unsigned short* vtss  = (unsigned short*)carve((size_t)64 * 512 * 2);
  unsigned short* ktst  = (unsigned short*)carve((size_t)64 * 512 * 2);
  unsigned short* vtst  = (unsigned short*)carve((size_t)64 * 512 * 2);
  unsigned short* Qb    = (unsigned short*)carve((size_t)M_TOK * 512 * 2);

  unsigned short* Kb = (unsigned short*)d_out;   // K/V bf16 + z1/z2 bf16 alias d_out
  unsigned short* Vb = Kb + (size_t)M_TOK * 512;
  float* outF = (float*)d_out;

  const bool bigws = ws_size >= (size_t)873725952ull;
  float* Rbuf = nullptr;
  unsigned short* Hb  = nullptr;   // [M][2048] bf16 FF hidden; early life: xb | rb1
  unsigned short* xb  = nullptr;
  unsigned short* rb1 = nullptr;
  if (bigws) {
    Hb = (unsigned short*)carve((size_t)M_TOK * 2048 * 2);
    xb = Hb;
    rb1 = Hb + (size_t)M_TOK * 512;
  } else {
    Rbuf = (float*)carve((size_t)M_TOK * 512 * 4);
  }

  const float QSCALE = 0.08838834764831845f; // 1/sqrt(128)

  {
    dim3 tb(32, 8);
    Tc8Args tc;
    tc.W[0] = sWq; tc.WT[0] = sQKVt;
    tc.W[1] = sWk; tc.WT[1] = sQKVt + 262144;
    tc.W[2] = sWv; tc.WT[2] = sQKVt + 524288;
    tc.W[3] = sWo; tc.WT[3] = sOT;
    tc.W[4] = tWq; tc.WT[4] = tQKVt;
    tc.W[5] = tWk; tc.WT[5] = tQKVt + 262144;
    tc.W[6] = tWv; tc.WT[6] = tQKVt + 524288;
    tc.W[7] = tWo; tc.WT[7] = tOT;
    tcast8_k<<<dim3(16, 16, 8), tb, 0, stream>>>(tc);
    tcast_k<<<dim3(64, 16), tb, 0, stream>>>(ffW1, W1T, 512, 2048);
    tcast_k<<<dim3(16, 64), tb, 0, stream>>>(ffW2, W2T, 2048, 512);
  }
  {
    TsArgs ta;
    ta.W[0] = sWk; ta.bias[0] = sbk; ta.out[0] = ktss;
    ta.W[1] = sWv; ta.bias[1] = sbv; ta.out[1] = vtss;
    ta.W[2] = tWk; ta.bias[2] = tbk; ta.out[2] = ktst;
    ta.W[3] = tWv; ta.bias[3] = tbv; ta.out[3] = vtst;
    tsproj_k<<<dim3(B_DIM, 2, 4), 1024, 0, stream>>>(tse, ta);
  }

  const int MT = M_TOK / 128;   // 1320 (fallback grids)
  const int MT2 = M_TOK / 256;  // 660  (256-row tiles; all grids %8==0)

  if (bigws) {
    // ---- spatial attention ----
    cast_k<<<2048, 256, 0, stream>>>(x, xb, M_TOK * 512 / 8);
    gemm256_k<EPI_QKV><<<12 * MT2, 512, 0, stream>>>(
        xb, sQKVt, sbq, sbk, sbv, nullptr, nullptr, Qb, Kb, Vb, 512, 512, 512, 512, 12, QSCALE);
    attn_s_k<<<dim3(F_DIM * B_DIM), 256, 0, stream>>>(Qb, Kb, Vb, ktss, vtss, Qb);
    // z1 = attnO@sWo + sbo + xb -> bf16 into Kb (K dead after attn_s; xb live)
    gemm256_k<EPI_RBB><<<4 * MT2, 512, 0, stream>>>(
        Qb, sOT, sbo, nullptr, nullptr, xb, nullptr, Kb, nullptr, nullptr, 512, 512, 512, 512, 4, 1.f);
    normb_k<<<M_TOK / 4, 256, 0, stream>>>(Kb, nullptr, rb1, n1a, n1b, 1);

    // ---- temporal attention ----
    gemm256_k<EPI_QKV><<<12 * MT2, 512, 0, stream>>>(
        rb1, tQKVt, tbq, tbk, tbv, nullptr, nullptr, Qb, Kb, Vb, 512, 512, 512, 512, 12, QSCALE);
    attn_t_k<<<dim3(J_DIM * B_DIM * H_DIM), 256, 0, stream>>>(Qb, Kb, Vb, ktst, vtst, Qb);
    // z2 = attnO@tWo + tbo + rb1 -> bf16 into Kb (K dead after attn_t)
    gemm256_k<EPI_RBB><<<4 * MT2, 512, 0, stream>>>(
        Qb, tOT, tbo, nullptr, nullptr, rb1, nullptr, Kb, nullptr, nullptr, 512, 512, 512, 512, 4, 1.f);
    normb_k<<<M_TOK / 4, 256, 0, stream>>>(Kb, nullptr, Qb, n2a, n2b, 2);

    // ---- feed-forward: gelu + K=2048 proj; z3 in-place in Qb ----
    gemm256_k<EPI_GELU><<<16 * MT2, 512, 0, stream>>>(
        Qb, W1T, ffb1, nullptr, nullptr, nullptr, nullptr, Hb, nullptr, nullptr,
        512, 512, 2048, 512, 16, 1.f);
    gemm256_k<EPI_RBB><<<4 * MT2, 512, 0, stream>>>(
        Hb, W2T, ffb2, nullptr, nullptr, Qb, nullptr, Qb, nullptr, nullptr,
        2048, 2048, 512, 2048, 4, 1.f);
    normb_k<<<M_TOK / 4, 256, 0, stream>>>(Qb, outF, nullptr, n3a, n3b, 0);
  } else {
    // ---- small-ws fallback (round-6 flow, f32 z-chain) ----
    gemmf_k<EPI_QKV><<<12 * MT, 256, 0, stream>>>(
        x, sQKVt, sbq, sbk, sbv, nullptr, nullptr, Qb, Kb, Vb, 512, 512, 512, 512, 12, QSCALE);
    attn_s_k<<<dim3(F_DIM * B_DIM), 256, 0, stream>>>(Qb, Kb, Vb, ktss, vtss, Qb);
    gemm_k<EPI_RES><<<4 * MT, 256, 0, stream>>>(
        Qb, sOT, sbo, nullptr, nullptr, x, outF, nullptr, nullptr, nullptr, 512, 512, 512, 512, 4, 1.f);
    norm_k<<<M_TOK / 4, 256, 0, stream>>>(outF, Rbuf, nullptr, n1a, n1b, 1);

    gemmf_k<EPI_QKV><<<12 * MT, 256, 0, stream>>>(
        Rbuf, tQKVt, tbq, tbk, tbv, nullptr, nullptr, Qb, Kb, Vb, 512, 512, 512, 512, 12, QSCALE);
    attn_t_k<<<dim3(J_DIM * B_DIM * H_DIM), 256, 0, stream>>>(Qb, Kb, Vb, ktst, vtst, Qb);
    gemm_k<EPI_RES><<<4 * MT, 256, 0, stream>>>(
        Qb, tOT, tbo, nullptr, nullptr, Rbuf, outF, nullptr, nullptr, nullptr, 512, 512, 512, 512, 4, 1.f);
    norm_k<<<M_TOK / 4, 256, 0, stream>>>(outF, Rbuf, Qb, n2a, n2b, 2);

    for (int c = 0; c < 4; ++c) {
      gemm_k<EPI_GELU><<<4 * MT, 256, 0, stream>>>(
          Qb, W1T + (size_t)c * 512 * 512, ffb1 + c * 512, nullptr, nullptr,
          nullptr, nullptr, Qb, nullptr, nullptr, 512, 512, 512, 512, 4, 1.f);
      if (c == 0)
        gemm_k<EPI_RES><<<4 * MT, 256, 0, stream>>>(
            Qb, W2T + c * 512, ffb2, nullptr, nullptr, Rbuf, outF,
            nullptr, nullptr, nullptr, 512, 2048, 512, 512, 4, 1.f);
      else
        gemm_k<EPI_ACC><<<4 * MT, 256, 0, stream>>>(
            Qb, W2T + c * 512, nullptr, nullptr, nullptr, nullptr, outF,
            nullptr, nullptr, nullptr, 512, 2048, 512, 512, 4, 1.f);
    }
    norm_k<<<M_TOK / 4, 256, 0, stream>>>(outF, outF, nullptr, n3a, n3b, 0);
  }
}

// Round 16
// 2699.202 us; speedup vs baseline: 1.3243x; 1.0084x over previous
//
#include <hip/hip_runtime.h>
#include <hip/hip_bf16.h>
#include <math.h>

// TransformerDecoder2dLayer on MI355X (gfx950).
// Round 16: epilogue VALU cut — gemm256 staged-epilogue conversions switched
// from hand-rolled integer f2b (3 ops, blocks cvt_pk fusion) to compiler
// __float2bfloat16 (RTNE, fuses to v_cvt_pk_bf16_f32); setprio(1) around the
// MFMA cluster (T5). Rest identical to round 15 (2722us).

#define F_DIM 120
#define B_DIM 64
#define J_DIM 22
#define H_DIM 4
#define M_TOK (F_DIM * B_DIM * J_DIM) // 168960

#define DEV static __device__ __forceinline__

typedef short bf16x8 __attribute__((ext_vector_type(8)));
typedef short us8 __attribute__((ext_vector_type(8)));
typedef float f32x4 __attribute__((ext_vector_type(4)));

struct __align__(8) us4 { unsigned short x, y, z, w; };

DEV unsigned short f2b(float f) {
  unsigned u = __float_as_uint(f);
  u += 0x7fffu + ((u >> 16) & 1u);
  return (unsigned short)(u >> 16);
}
DEV unsigned short f2bc(float f) {   // compiler cast: fuses to v_cvt_pk_bf16_f32
  __hip_bfloat16 h = __float2bfloat16(f);
  return *(unsigned short*)&h;
}
DEV float b2f(unsigned short u) { return __uint_as_float(((unsigned)u) << 16); }

#define GLOAD16(g, l)                                                          \
  __builtin_amdgcn_global_load_lds(                                            \
      (const __attribute__((address_space(1))) void*)(g),                      \
      (__attribute__((address_space(3))) void*)(l), 16, 0, 0)

enum { EPI_QKV = 0, EPI_GELU = 1, EPI_RES = 2, EPI_ACC = 3, EPI_RESB = 4,
       EPI_ROB = 5, EPI_RBB = 6 };

// ---------------------------------------------------------------------------
__global__ __launch_bounds__(256)
void cast_k(const float* __restrict__ in, unsigned short* __restrict__ out, int n8) {
  for (int i = blockIdx.x * 256 + threadIdx.x; i < n8; i += gridDim.x * 256) {
    const float4 a = ((const float4*)in)[i * 2];
    const float4 b = ((const float4*)in)[i * 2 + 1];
    us8 v;
    v[0] = f2b(a.x); v[1] = f2b(a.y); v[2] = f2b(a.z); v[3] = f2b(a.w);
    v[4] = f2b(b.x); v[5] = f2b(b.y); v[6] = f2b(b.z); v[7] = f2b(b.w);
    __builtin_nontemporal_store(v, (us8*)&out[i * 8]);
  }
}

// ---------------------------------------------------------------------------
__global__ __launch_bounds__(256)
void tcast_k(const float* __restrict__ W, unsigned short* __restrict__ WT, int K, int N) {
  __shared__ float t[32][33];
  const int n0 = blockIdx.x * 32, k0 = blockIdx.y * 32;
  const int tx = threadIdx.x, ty = threadIdx.y;
#pragma unroll
  for (int i = 0; i < 4; ++i)
    t[ty + i * 8][tx] = W[(size_t)(k0 + ty + i * 8) * N + n0 + tx];
  __syncthreads();
#pragma unroll
  for (int i = 0; i < 4; ++i)
    WT[(size_t)(n0 + ty + i * 8) * K + k0 + tx] = f2b(t[tx][ty + i * 8]);
}

struct Tc8Args { const float* W[8]; unsigned short* WT[8]; };
__global__ __launch_bounds__(256)
void tcast8_k(Tc8Args a) {
  __shared__ float t[32][33];
  const float* W = a.W[blockIdx.z];
  unsigned short* WT = a.WT[blockIdx.z];
  const int n0 = blockIdx.x * 32, k0 = blockIdx.y * 32;
  const int tx = threadIdx.x, ty = threadIdx.y;
#pragma unroll
  for (int i = 0; i < 4; ++i)
    t[ty + i * 8][tx] = W[(size_t)(k0 + ty + i * 8) * 512 + n0 + tx];
  __syncthreads();
#pragma unroll
  for (int i = 0; i < 4; ++i)
    WT[(size_t)(n0 + ty + i * 8) * 512 + k0 + tx] = f2b(t[tx][ty + i * 8]);
}

// ---------------------------------------------------------------------------
struct TsArgs { const float* W[4]; const float* bias[4]; unsigned short* out[4]; };
__global__ __launch_bounds__(1024)
void tsproj_k(const float* __restrict__ ts, TsArgs a) {
  __shared__ float tsr[512];
  __shared__ float red[3][256];
  const int b = blockIdx.x;
  const int nb = blockIdx.y;
  const int pj = blockIdx.z;
  const int t = threadIdx.x;
  const int n = nb * 256 + (t & 255);
  const int kh = t >> 8;
  if (t < 512) tsr[t] = ts[b * 512 + t];
  __syncthreads();
  const float* W = a.W[pj];
  float acc = 0.f;
  const int k0 = kh * 128;
  for (int k = k0; k < k0 + 128; ++k)
    acc += tsr[k] * W[(size_t)k * 512 + n];
  if (kh) red[kh - 1][t & 255] = acc;
  __syncthreads();
  if (kh == 0) {
    acc += red[0][t & 255] + red[1][t & 255] + red[2][t & 255];
    a.out[pj][b * 512 + n] = f2b(acc + a.bias[pj][n]);
  }
}

// ---------------------------------------------------------------------------
// Scalar epilogue op — fallback kernels only.
template<int EPI>
DEV void epi_store(float v, int row, int col, const float* b0, const float* b1,
                   const float* b2, const void* res, float* outF,
                   unsigned short* o0, unsigned short* o1, unsigned short* o2,
                   int ldo, float scale) {
  if constexpr (EPI == EPI_QKV) {
    const int seg = col >> 9;
    const int cl = col & 511;
    const float* bs = (seg == 0) ? b0 : (seg == 1) ? b1 : b2;
    unsigned short* ob = (seg == 0) ? o0 : (seg == 1) ? o1 : o2;
    const float sc = (seg == 0) ? scale : 1.f;
    v = (v + bs[cl]) * sc;
    ob[(size_t)row * 512 + cl] = f2b(v);
  } else if constexpr (EPI == EPI_GELU) {
    v += b0[col];
    const float a2 = 1.5957691216057308f * (v + 0.044715f * v * v * v);
    const float g = v / (1.f + __expf(-a2));
    o0[(size_t)row * ldo + col] = f2b(g);
  } else if constexpr (EPI == EPI_RES) {
    const size_t off = (size_t)row * 512 + col;
    outF[off] = v + b0[col] + ((const float*)res)[off];
  } else if constexpr (EPI == EPI_RESB) {
    const size_t off = (size_t)row * 512 + col;
    outF[off] = v + b0[col] + b2f(((const unsigned short*)res)[off]);
  } else if constexpr (EPI == EPI_ROB) {
    const size_t off = (size_t)row * 512 + col;
    o0[off] = f2b(v + b0[col] + ((const float*)res)[off]);
  } else if constexpr (EPI == EPI_RBB) {
    const size_t off = (size_t)row * 512 + col;
    o0[off] = f2b(v + b0[col] + b2f(((const unsigned short*)res)[off]));
  } else { // EPI_ACC
    const size_t off = (size_t)row * 512 + col;
    outF[off] = v + outF[off];
  }
}

// ---------------------------------------------------------------------------
// 256x128 GEMM, BK=32, 8 waves (4m x 2n) of 64x64; triple-buffered LDS in a
// unified SMEM block, counted vmcnt(3), 1 s_barrier/step, setprio around
// the MFMA cluster. Epilogue (QKV/GELU/RBB): all 8 waves write the full
// 256x128 bf16 tile into SMEM (granule-XOR swizzle) concurrently (compiler
// bf16 casts -> v_cvt_pk fusion), one __syncthreads, one us8-nt stream pass.
template<int EPI>
__global__ __launch_bounds__(512, 4)
void gemm256_k(const unsigned short* __restrict__ Ab, const unsigned short* __restrict__ Wt,
               const float* __restrict__ b0, const float* __restrict__ b1, const float* __restrict__ b2,
               const void* __restrict__ res, float* __restrict__ outF,
               unsigned short* __restrict__ o0, unsigned short* __restrict__ o1, unsigned short* __restrict__ o2,
               int lda, int ldw, int ldo, int nk, int nx, float scale) {
  __shared__ unsigned short SMEM[36864];   // 72KB: A 3x8192 | B 3x4096 ; Ot post-loop
  const int tid = threadIdx.x;
  const int chunkg = gridDim.x >> 3;       // XCD-chunked bijective swizzle (nwg%8==0)
  const int wg = (blockIdx.x & 7) * chunkg + (blockIdx.x >> 3);
  const int nbase = (wg % nx) * 128;
  const int mbase = (wg / nx) * 256;
  const int lane = tid & 63;
  const int w = tid >> 6;
  const int wr = (w >> 1) * 64;
  const int wc = (w & 1) * 64;
  const int l15 = lane & 15;
  const int lhi = lane >> 4;

  const int crow = lane >> 2;
  const int ccol = (((lane & 3) ^ ((lane >> 3) & 3)) << 3);
  const unsigned short* gA0 = Ab + (size_t)(mbase + 32 * w + crow) * lda + ccol;
  const unsigned short* gA1 = gA0 + (size_t)16 * lda;
  const unsigned short* gB0 = Wt + (size_t)(nbase + 16 * w + crow) * ldw + ccol;

  auto Asb = [&](int bb) { return &SMEM[bb * 8192]; };
  auto Bsb = [&](int bb) { return &SMEM[24576 + bb * 4096]; };

  auto stage = [&](int bb, int kt) {   // 3 vmem ops / wave
    GLOAD16(gA0 + kt, &Asb(bb)[(2 * w) * 512]);
    GLOAD16(gA1 + kt, &Asb(bb)[(2 * w + 1) * 512]);
    GLOAD16(gB0 + kt, &Bsb(bb)[w * 512]);
  };

  f32x4 acc[4][4] = {};
  const int KT = nk >> 5;
  const int swz = ((lhi ^ ((l15 >> 1) & 3)) << 3);

  stage(0, 0);
  stage(1, 32);
  asm volatile("s_waitcnt vmcnt(3)" ::: "memory");
  __builtin_amdgcn_s_barrier();

  for (int t = 0; t < KT; ++t) {
    const unsigned short* as = Asb(t % 3);
    const unsigned short* bs = Bsb(t % 3);
    if (t + 2 < KT) stage((t + 2) % 3, (t + 2) << 5);
    bf16x8 afr[4], bfr[4];
#pragma unroll
    for (int i = 0; i < 4; ++i) afr[i] = *(const bf16x8*)&as[(wr + i * 16 + l15) * 32 + swz];
#pragma unroll
    for (int j = 0; j < 4; ++j) bfr[j] = *(const bf16x8*)&bs[(wc + j * 16 + l15) * 32 + swz];
    __builtin_amdgcn_s_setprio(1);
#pragma unroll
    for (int i = 0; i < 4; ++i)
#pragma unroll
      for (int j = 0; j < 4; ++j)
        acc[i][j] = __builtin_amdgcn_mfma_f32_16x16x32_bf16(afr[i], bfr[j], acc[i][j], 0, 0, 0);
    __builtin_amdgcn_s_setprio(0);
    if (t + 2 < KT)      asm volatile("s_waitcnt vmcnt(3) lgkmcnt(0)" ::: "memory");
    else if (t + 1 < KT) asm volatile("s_waitcnt vmcnt(0) lgkmcnt(0)" ::: "memory");
    else                 asm volatile("s_waitcnt lgkmcnt(0)" ::: "memory");
    __builtin_amdgcn_s_barrier();
  }

  if constexpr (EPI == EPI_QKV || EPI == EPI_GELU || EPI == EPI_RBB) {
    // ---- single-phase staged vectorized epilogue ----
    unsigned short* Ot = &SMEM[0];   // 36864 shorts free; full tile needs 32768
    const int seg = (EPI == EPI_QKV) ? (nbase >> 9) : 0;   // tile fits one segment
    unsigned short* ob = (EPI == EPI_QKV) ? ((seg == 0) ? o0 : (seg == 1) ? o1 : o2) : o0;
    const float* bb = (EPI == EPI_QKV) ? ((seg == 0) ? b0 : (seg == 1) ? b1 : b2) : b0;
    const float sc = (EPI == EPI_QKV && 0 == seg) ? scale : 1.f;
    const int cb = (EPI == EPI_QKV) ? (nbase & 511) : nbase;
    // write phase: all 8 waves, disjoint quadrants of the 256x128 tile
#pragma unroll
    for (int i = 0; i < 4; ++i)
#pragma unroll
      for (int j = 0; j < 4; ++j) {
        const int c = wc + j * 16 + l15;
#pragma unroll
        for (int q = 0; q < 4; ++q) {
          const int row = wr + i * 16 + (lhi << 2) + q;
          float v = acc[i][j][q];
          if constexpr (EPI == EPI_QKV) {
            v = (v + bb[cb + c]) * sc;
          } else if constexpr (EPI == EPI_GELU) {
            v += bb[cb + c];
            const float a2 = 1.5957691216057308f * (v + 0.044715f * v * v * v);
            v = v / (1.f + __expf(-a2));
          } else {  // RBB: bias now, residual in stream phase
            v += bb[cb + c];
          }
          Ot[(row << 7) + ((((c >> 3) ^ (row & 7)) << 3) | (c & 7))] = f2bc(v);
        }
      }
    __syncthreads();   // full fence: ds_writes visible to all threads
#pragma unroll
    for (int ps = 0; ps < 8; ++ps) {   // 8 x 512 thr x 16B = 64KB full tile
      const int idx = (ps * 512 + tid) * 8;
      const int row = idx >> 7;
      const int c = idx & 127;
      us8 val = *(const us8*)&Ot[(row << 7) + (((c >> 3) ^ (row & 7)) << 3)];
      const size_t grow = (size_t)(mbase + row);
      const int gcol = cb + c;
      if constexpr (EPI == EPI_RBB) {
        const us8 r = __builtin_nontemporal_load(
            (const us8*)&((const unsigned short*)res)[grow * 512 + gcol]);
#pragma unroll
        for (int e = 0; e < 8; ++e)
          val[e] = (short)f2bc(b2f((unsigned short)val[e]) + b2f((unsigned short)r[e]));
      }
      __builtin_nontemporal_store(val, (us8*)&ob[grow * ldo + gcol]);
    }
  } else {
#pragma unroll
    for (int i = 0; i < 4; ++i)
#pragma unroll
      for (int j = 0; j < 4; ++j) {
        const int row0 = mbase + wr + i * 16 + (lhi << 2);
        const int col = nbase + wc + j * 16 + l15;
#pragma unroll
        for (int q = 0; q < 4; ++q)
          epi_store<EPI>(acc[i][j][q], row0 + q, col, b0, b1, b2, res, outF, o0, o1, o2, ldo, scale);
      }
  }
}

// ---------------------------------------------------------------------------
// 128x128 pipelined GEMM — small-ws fallback path.
template<int EPI>
__global__ __launch_bounds__(256)
void gemm_k(const unsigned short* __restrict__ Ab, const unsigned short* __restrict__ Wt,
            const float* __restrict__ b0, const float* __restrict__ b1, const float* __restrict__ b2,
            const void* __restrict__ res, float* __restrict__ outF,
            unsigned short* __restrict__ o0, unsigned short* __restrict__ o1, unsigned short* __restrict__ o2,
            int lda, int ldw, int ldo, int nk, int nx, float scale) {
  __shared__ unsigned short As[3][4096];
  __shared__ unsigned short Bs[3][4096];
  const int tid = threadIdx.x;
  const int chunkg = gridDim.x >> 3;
  const int wg = (blockIdx.x & 7) * chunkg + (blockIdx.x >> 3);
  const int nbase = (wg % nx) * 128;
  const int mbase = (wg / nx) * 128;
  const int lane = tid & 63;
  const int w = tid >> 6;
  const int wr = (w >> 1) * 64;
  const int wc = (w & 1) * 64;
  const int l15 = lane & 15;
  const int lhi = lane >> 4;

  const int crow = lane >> 2;
  const int ccol = (((lane & 3) ^ ((lane >> 3) & 3)) << 3);
  const unsigned short* gA0 = Ab + (size_t)(mbase + 32 * w + crow) * lda + ccol;
  const unsigned short* gA1 = gA0 + (size_t)16 * lda;
  const unsigned short* gB0 = Wt + (size_t)(nbase + 32 * w + crow) * ldw + ccol;
  const unsigned short* gB1 = gB0 + (size_t)16 * ldw;

  auto stage = [&](int bb, int kt) {
    GLOAD16(gA0 + kt, &As[bb][(2 * w) * 512]);
    GLOAD16(gA1 + kt, &As[bb][(2 * w + 1) * 512]);
    GLOAD16(gB0 + kt, &Bs[bb][(2 * w) * 512]);
    GLOAD16(gB1 + kt, &Bs[bb][(2 * w + 1) * 512]);
  };

  f32x4 acc[4][4] = {};
  const int KT = nk >> 5;
  const int swz = ((lhi ^ ((l15 >> 1) & 3)) << 3);

  stage(0, 0);
  stage(1, 32);
  asm volatile("s_waitcnt vmcnt(4)" ::: "memory");
  __builtin_amdgcn_s_barrier();

  for (int t = 0; t < KT; ++t) {
    const unsigned short* as = As[t % 3];
    const unsigned short* bs = Bs[t % 3];
    if (t + 2 < KT) stage((t + 2) % 3, (t + 2) << 5);
    bf16x8 afr[4], bfr[4];
#pragma unroll
    for (int i = 0; i < 4; ++i) afr[i] = *(const bf16x8*)&as[(wr + i * 16 + l15) * 32 + swz];
#pragma unroll
    for (int j = 0; j < 4; ++j) bfr[j] = *(const bf16x8*)&bs[(wc + j * 16 + l15) * 32 + swz];
#pragma unroll
    for (int i = 0; i < 4; ++i)
#pragma unroll
      for (int j = 0; j < 4; ++j)
        acc[i][j] = __builtin_amdgcn_mfma_f32_16x16x32_bf16(afr[i], bfr[j], acc[i][j], 0, 0, 0);
    if (t + 2 < KT)      asm volatile("s_waitcnt vmcnt(4) lgkmcnt(0)" ::: "memory");
    else if (t + 1 < KT) asm volatile("s_waitcnt vmcnt(0) lgkmcnt(0)" ::: "memory");
    else                 asm volatile("s_waitcnt lgkmcnt(0)" ::: "memory");
    __builtin_amdgcn_s_barrier();
  }

#pragma unroll
  for (int i = 0; i < 4; ++i)
#pragma unroll
    for (int j = 0; j < 4; ++j) {
      const int row0 = mbase + wr + i * 16 + (lhi << 2);
      const int col = nbase + wc + j * 16 + l15;
#pragma unroll
      for (int q = 0; q < 4; ++q)
        epi_store<EPI>(acc[i][j][q], row0 + q, col, b0, b1, b2, res, outF, o0, o1, o2, ldo, scale);
    }
}

// ---------------------------------------------------------------------------
// Legacy reg-staging GEMM for f32 A (small-ws fallback only).
template<int EPI>
__global__ __launch_bounds__(256)
void gemmf_k(const float* __restrict__ Af, const unsigned short* __restrict__ Wt,
             const float* __restrict__ b0, const float* __restrict__ b1, const float* __restrict__ b2,
             const void* __restrict__ res, float* __restrict__ outF,
             unsigned short* __restrict__ o0, unsigned short* __restrict__ o1, unsigned short* __restrict__ o2,
             int lda, int ldw, int ldo, int nk, int nx, float scale) {
  __shared__ unsigned short As[128][40];
  __shared__ unsigned short Bs[128][40];
  const int tid = threadIdx.x;
  const int chunkg = gridDim.x >> 3;
  const int wg = (blockIdx.x & 7) * chunkg + (blockIdx.x >> 3);
  const int nbase = (wg % nx) * 128;
  const int mbase = (wg / nx) * 128;
  const int lane = tid & 63;
  const int w = tid >> 6;
  const int wr = (w >> 1) * 64;
  const int wc = (w & 1) * 64;
  const int l15 = lane & 15;
  const int lhi = lane >> 4;

  float4 ra[4];
  us4 rb[4];
  auto loadAB = [&](int kt) {
#pragma unroll
    for (int i = 0; i < 4; ++i) {
      const int g = i * 256 + tid;
      const int r = g >> 3;
      const int c = (g & 7) << 2;
      ra[i] = *(const float4*)(Af + (size_t)(mbase + r) * lda + kt + c);
      rb[i] = *(const us4*)(Wt + (size_t)(nbase + r) * ldw + kt + c);
    }
  };
  auto storeAB = [&]() {
#pragma unroll
    for (int i = 0; i < 4; ++i) {
      const int g = i * 256 + tid;
      const int r = g >> 3;
      const int c = (g & 7) << 2;
      us4 ua;
      ua.x = f2b(ra[i].x); ua.y = f2b(ra[i].y); ua.z = f2b(ra[i].z); ua.w = f2b(ra[i].w);
      *(us4*)&As[r][c] = ua;
      *(us4*)&Bs[r][c] = rb[i];
    }
  };

  f32x4 acc[4][4] = {};
  const int KT = nk >> 5;
  loadAB(0);
  storeAB();
  __syncthreads();
  for (int t = 0; t < KT; ++t) {
    if (t + 1 < KT) loadAB((t + 1) << 5);
    bf16x8 afr[4], bfr[4];
    const int klo = lhi << 3;
#pragma unroll
    for (int i = 0; i < 4; ++i) afr[i] = *(const bf16x8*)&As[wr + i * 16 + l15][klo];
#pragma unroll
    for (int j = 0; j < 4; ++j) bfr[j] = *(const bf16x8*)&Bs[wc + j * 16 + l15][klo];
#pragma unroll
    for (int i = 0; i < 4; ++i)
#pragma unroll
      for (int j = 0; j < 4; ++j)
        acc[i][j] = __builtin_amdgcn_mfma_f32_16x16x32_bf16(afr[i], bfr[j], acc[i][j], 0, 0, 0);
    __syncthreads();
    if (t + 1 < KT) { storeAB(); __syncthreads(); }
  }

#pragma unroll
  for (int i = 0; i < 4; ++i)
#pragma unroll
    for (int j = 0; j < 4; ++j) {
      const int row0 = mbase + wr + i * 16 + (lhi << 2);
      const int col = nbase + wc + j * 16 + l15;
#pragma unroll
      for (int q = 0; q < 4; ++q)
        epi_store<EPI>(acc[i][j][q], row0 + q, col, b0, b1, b2, res, outF, o0, o1, o2, ldo, scale);
    }
}

// ---------------------------------------------------------------------------
// Temporal MFMA attention. Block = (instance, head): 1408*4 blocks, 4 waves.
__global__ __launch_bounds__(256)
void attn_t_k(const unsigned short* __restrict__ Qb, const unsigned short* __restrict__ Kb,
              const unsigned short* __restrict__ Vb, const unsigned short* __restrict__ kts,
              const unsigned short* __restrict__ vts, unsigned short* __restrict__ Ob) {
  __shared__ unsigned short Ps[128][134];
  __shared__ unsigned short Vt[64][134];
  const int tid = threadIdx.x;
  const int inst = blockIdx.x >> 2;
  const int h = blockIdx.x & 3;
  const int b = inst & (B_DIM - 1);
  const size_t rowbase = (size_t)inst * 120;
  const int hoff = h * 128;
  const int lane = tid & 63;
  const int w = tid >> 6;
  const int wr = w * 32;
  const int l15 = lane & 15;
  const int lhi = lane >> 4;

  auto stageV = [&](int half) {
    for (int e = tid; e < 2048; e += 256) {
      const int d4 = (e & 15) << 2;
      const int key = e >> 4;
      us4 v;
      if (key <= 120) {
        const unsigned short* src = (key == 0) ? (vts + b * 512) : (Vb + (rowbase + key - 1) * 512);
        v = *(const us4*)(src + hoff + half * 64 + d4);
      } else { v.x = 0; v.y = 0; v.z = 0; v.w = 0; }
      Vt[d4 + 0][key] = v.x; Vt[d4 + 1][key] = v.y; Vt[d4 + 2][key] = v.z; Vt[d4 + 3][key] = v.w;
    }
  };
  stageV(0);

  bf16x8 qa[2][4];
#pragma unroll
  for (int i = 0; i < 2; ++i) {
    const int row = min(wr + i * 16 + l15, 119);
    const unsigned short* qp = Qb + (rowbase + row) * 512 + hoff;
#pragma unroll
    for (int kt = 0; kt < 4; ++kt)
      qa[i][kt] = *(const bf16x8*)(qp + kt * 32 + lhi * 8);
  }

  f32x4 acc[2][8] = {};
#pragma unroll
  for (int kt = 0; kt < 4; ++kt) {
    const int klo = kt * 32 + lhi * 8;
    bf16x8 kb[8];
#pragma unroll
    for (int j = 0; j < 8; ++j) {
      const int key = min(j * 16 + l15, 120);
      const unsigned short* kp = (key == 0) ? (kts + b * 512) : (Kb + (rowbase + key - 1) * 512);
      kb[j] = *(const bf16x8*)(kp + hoff + klo);
    }
#pragma unroll
    for (int i = 0; i < 2; ++i)
#pragma unroll
      for (int j = 0; j < 8; ++j)
        acc[i][j] = __builtin_amdgcn_mfma_f32_16x16x32_bf16(qa[i][kt], kb[j], acc[i][j], 0, 0, 0);
  }

  float rinv[2][4];
#pragma unroll
  for (int i = 0; i < 2; ++i)
#pragma unroll
    for (int q = 0; q < 4; ++q) {
      float m = -1e30f;
#pragma unroll
      for (int j = 0; j < 8; ++j)
        if (j * 16 + l15 <= 120) m = fmaxf(m, acc[i][j][q]);
#pragma unroll
      for (int mk = 1; mk < 16; mk <<= 1) m = fmaxf(m, __shfl_xor(m, mk, 64));
      float s = 0.f;
#pragma unroll
      for (int j = 0; j < 8; ++j) {
        const float e = (j * 16 + l15 <= 120) ? __expf(acc[i][j][q] - m) : 0.f;
        acc[i][j][q] = e; s += e;
      }
#pragma unroll
      for (int mk = 1; mk < 16; mk <<= 1) s += __shfl_xor(s, mk, 64);
      rinv[i][q] = 1.f / s;
    }

#pragma unroll
  for (int i = 0; i < 2; ++i)
#pragma unroll
    for (int j = 0; j < 8; ++j)
#pragma unroll
      for (int q = 0; q < 4; ++q)
        Ps[wr + i * 16 + lhi * 4 + q][j * 16 + l15] = f2b(acc[i][j][q]);

  __syncthreads();

#pragma unroll
  for (int half = 0; half < 2; ++half) {
    if (half == 1) {
      __syncthreads();
      stageV(1);
      __syncthreads();
    }
    f32x4 oac[2][4] = {};
#pragma unroll
    for (int kt = 0; kt < 4; ++kt) {
      const int klo = kt * 32 + lhi * 8;
      bf16x8 pa[2], vb[4];
#pragma unroll
      for (int i = 0; i < 2; ++i) pa[i] = *(const bf16x8*)&Ps[wr + i * 16 + l15][klo];
#pragma unroll
      for (int jd = 0; jd < 4; ++jd) vb[jd] = *(const bf16x8*)&Vt[jd * 16 + l15][klo];
#pragma unroll
      for (int i = 0; i < 2; ++i)
#pragma unroll
        for (int jd = 0; jd < 4; ++jd)
          oac[i][jd] = __builtin_amdgcn_mfma_f32_16x16x32_bf16(pa[i], vb[jd], oac[i][jd], 0, 0, 0);
    }
#pragma unroll
    for (int i = 0; i < 2; ++i)
#pragma unroll
      for (int q = 0; q < 4; ++q) {
        const int r = wr + i * 16 + lhi * 4 + q;
        if (r < 120) {
          const float sc = rinv[i][q];
#pragma unroll
          for (int jd = 0; jd < 4; ++jd)
            Ob[(rowbase + r) * 512 + hoff + half * 64 + jd * 16 + l15] = f2b(oac[i][jd][q] * sc);
        }
      }
  }
}

// ---------------------------------------------------------------------------
// Spatial MFMA attention. Block = (f,b) instance (7680 blocks), wave = head.
__global__ __launch_bounds__(256)
void attn_s_k(const unsigned short* __restrict__ Qb, const unsigned short* __restrict__ Kb,
              const unsigned short* __restrict__ Vb, const unsigned short* __restrict__ kts,
              const unsigned short* __restrict__ vts, unsigned short* __restrict__ Ob) {
  __shared__ unsigned short Ps[4][32][34];
  __shared__ unsigned short Vt[4][128][34];
  const int tid = threadIdx.x;
  const int inst = blockIdx.x;
  const int b = inst & (B_DIM - 1);
  const size_t rowbase = (size_t)inst * 22;
  const int lane = tid & 63;
  const int h = tid >> 6;
  const int l15 = lane & 15;
  const int lhi = lane >> 4;
  const int hoff = h * 128;

  for (int e = tid; e < 4096; e += 256) {
    const int h2 = e >> 10;
    const int rem = e & 1023;
    const int key = rem >> 5;
    const int d4 = (rem & 31) << 2;
    us4 v;
    if (key <= 22) {
      const unsigned short* src = (key == 0) ? (vts + b * 512) : (Vb + (rowbase + key - 1) * 512);
      v = *(const us4*)(src + h2 * 128 + d4);
    } else { v.x = 0; v.y = 0; v.z = 0; v.w = 0; }
    Vt[h2][d4 + 0][key] = v.x; Vt[h2][d4 + 1][key] = v.y; Vt[h2][d4 + 2][key] = v.z; Vt[h2][d4 + 3][key] = v.w;
  }

  bf16x8 qa[2][4];
#pragma unroll
  for (int i = 0; i < 2; ++i) {
    const int row = min(i * 16 + l15, 21);
    const unsigned short* qp = Qb + (rowbase + row) * 512 + hoff;
#pragma unroll
    for (int kt = 0; kt < 4; ++kt)
      qa[i][kt] = *(const bf16x8*)(qp + kt * 32 + lhi * 8);
  }

  f32x4 acc[2][2] = {};
#pragma unroll
  for (int kt = 0; kt < 4; ++kt) {
    const int klo = kt * 32 + lhi * 8;
    bf16x8 kb[2];
#pragma unroll
    for (int j = 0; j < 2; ++j) {
      const int key = min(j * 16 + l15, 22);
      const unsigned short* kp = (key == 0) ? (kts + b * 512) : (Kb + (rowbase + key - 1) * 512);
      kb[j] = *(const bf16x8*)(kp + hoff + klo);
    }
#pragma unroll
    for (int i = 0; i < 2; ++i)
#pragma unroll
      for (int j = 0; j < 2; ++j)
        acc[i][j] = __builtin_amdgcn_mfma_f32_16x16x32_bf16(qa[i][kt], kb[j], acc[i][j], 0, 0, 0);
  }

  float rinv[2][4];
#pragma unroll
  for (int i = 0; i < 2; ++i)
#pragma unroll
    for (int q = 0; q < 4; ++q) {
      float m = -1e30f;
#pragma unroll
      for (int j = 0; j < 2; ++j)
        if (j * 16 + l15 <= 22) m = fmaxf(m, acc[i][j][q]);
#pragma unroll
      for (int mk = 1; mk < 16; mk <<= 1) m = fmaxf(m, __shfl_xor(m, mk, 64));
      float s = 0.f;
#pragma unroll
      for (int j = 0; j < 2; ++j) {
        const float e = (j * 16 + l15 <= 22) ? __expf(acc[i][j][q] - m) : 0.f;
        acc[i][j][q] = e; s += e;
      }
#pragma unroll
      for (int mk = 1; mk < 16; mk <<= 1) s += __shfl_xor(s, mk, 64);
      rinv[i][q] = 1.f / s;
    }

#pragma unroll
  for (int i = 0; i < 2; ++i)
#pragma unroll
    for (int j = 0; j < 2; ++j)
#pragma unroll
      for (int q = 0; q < 4; ++q)
        Ps[h][i * 16 + lhi * 4 + q][j * 16 + l15] = f2b(acc[i][j][q]);

  __syncthreads();

  f32x4 oac[2][8] = {};
  {
    const int klo = lhi * 8;
    bf16x8 pa[2];
#pragma unroll
    for (int i = 0; i < 2; ++i) pa[i] = *(const bf16x8*)&Ps[h][i * 16 + l15][klo];
#pragma unroll
    for (int jd = 0; jd < 8; ++jd) {
      const bf16x8 vb = *(const bf16x8*)&Vt[h][jd * 16 + l15][klo];
#pragma unroll
      for (int i = 0; i < 2; ++i)
        oac[i][jd] = __builtin_amdgcn_mfma_f32_16x16x32_bf16(pa[i], vb, oac[i][jd], 0, 0, 0);
    }
  }

#pragma unroll
  for (int i = 0; i < 2; ++i)
#pragma unroll
    for (int q = 0; q < 4; ++q) {
      const int r = i * 16 + lhi * 4 + q;
      if (r < 22) {
        const float sc = rinv[i][q];
#pragma unroll
        for (int jd = 0; jd < 8; ++jd)
          Ob[(rowbase + r) * 512 + hoff + jd * 16 + l15] = f2b(oac[i][jd][q] * sc);
      }
    }
}

// ---------------------------------------------------------------------------
// Row norm (ddof=1, eps on sd), f32 input — fallback path.
__global__ __launch_bounds__(256)
void norm_k(const float* __restrict__ in, float* __restrict__ out,
            unsigned short* __restrict__ outB,
            const float* __restrict__ ga, const float* __restrict__ gb, const int mode) {
  const int r = blockIdx.x * 4 + (threadIdx.x >> 6);
  const int lane = threadIdx.x & 63;
  const float* row = in + (size_t)r * 512;
  const float4 v0 = *(const float4*)&row[lane * 4];
  const float4 v1 = *(const float4*)&row[256 + lane * 4];
  float s = v0.x + v0.y + v0.z + v0.w + v1.x + v1.y + v1.z + v1.w;
  float ss = v0.x * v0.x + v0.y * v0.y + v0.z * v0.z + v0.w * v0.w
           + v1.x * v1.x + v1.y * v1.y + v1.z * v1.z + v1.w * v1.w;
#pragma unroll
  for (int m = 1; m < 64; m <<= 1) { s += __shfl_xor(s, m, 64); ss += __shfl_xor(ss, m, 64); }
  const float mean = s * (1.f / 512.f);
  const float var = (ss - 512.f * mean * mean) * (1.f / 511.f);
  const float inv = 1.f / (sqrtf(fmaxf(var, 0.f)) + 1e-6f);
  int ro;
  if (mode == 0) ro = r;
  else if (mode == 1) {
    const int f = r / (B_DIM * J_DIM);
    const int bb = (r / J_DIM) % B_DIM;
    const int j = r % J_DIM;
    ro = (j * B_DIM + bb) * F_DIM + f;
  } else {
    const int j = r / (B_DIM * F_DIM);
    const int bb = (r / F_DIM) % B_DIM;
    const int f = r % F_DIM;
    ro = (f * B_DIM + bb) * J_DIM + j;
  }
  const float4 g0 = *(const float4*)&ga[lane * 4];
  const float4 g1 = *(const float4*)&ga[256 + lane * 4];
  const float4 h0 = *(const float4*)&gb[lane * 4];
  const float4 h1 = *(const float4*)&gb[256 + lane * 4];
  float4 y0, y1;
  y0.x = g0.x * (v0.x - mean) * inv + h0.x;
  y0.y = g0.y * (v0.y - mean) * inv + h0.y;
  y0.z = g0.z * (v0.z - mean) * inv + h0.z;
  y0.w = g0.w * (v0.w - mean) * inv + h0.w;
  y1.x = g1.x * (v1.x - mean) * inv + h1.x;
  y1.y = g1.y * (v1.y - mean) * inv + h1.y;
  y1.z = g1.z * (v1.z - mean) * inv + h1.z;
  y1.w = g1.w * (v1.w - mean) * inv + h1.w;
  if (out) {
    float* orow = out + (size_t)ro * 512;
    *(float4*)&orow[lane * 4] = y0;
    *(float4*)&orow[256 + lane * 4] = y1;
  }
  if (outB) {
    us4 a, b;
    a.x = f2b(y0.x); a.y = f2b(y0.y); a.z = f2b(y0.z); a.w = f2b(y0.w);
    b.x = f2b(y1.x); b.y = f2b(y1.y); b.z = f2b(y1.z); b.w = f2b(y1.w);
    *(us4*)&outB[(size_t)ro * 512 + lane * 4] = a;
    *(us4*)&outB[(size_t)ro * 512 + 256 + lane * 4] = b;
  }
}

// ---------------------------------------------------------------------------
// Row norm, bf16 input (one us8/lane). Optional f32 out and/or bf16 out.
__global__ __launch_bounds__(256)
void normb_k(const unsigned short* __restrict__ in, float* __restrict__ out,
             unsigned short* __restrict__ outB,
             const float* __restrict__ ga, const float* __restrict__ gb, const int mode) {
  const int r = blockIdx.x * 4 + (threadIdx.x >> 6);
  const int lane = threadIdx.x & 63;
  const us8 wv = *(const us8*)&in[(size_t)r * 512 + lane * 8];
  float v[8];
  float s = 0.f, ss = 0.f;
#pragma unroll
  for (int e = 0; e < 8; ++e) {
    v[e] = b2f((unsigned short)wv[e]);
    s += v[e]; ss += v[e] * v[e];
  }
#pragma unroll
  for (int m = 1; m < 64; m <<= 1) { s += __shfl_xor(s, m, 64); ss += __shfl_xor(ss, m, 64); }
  const float mean = s * (1.f / 512.f);
  const float var = (ss - 512.f * mean * mean) * (1.f / 511.f);
  const float inv = 1.f / (sqrtf(fmaxf(var, 0.f)) + 1e-6f);
  int ro;
  if (mode == 0) ro = r;
  else if (mode == 1) {
    const int f = r / (B_DIM * J_DIM);
    const int bb = (r / J_DIM) % B_DIM;
    const int j = r % J_DIM;
    ro = (j * B_DIM + bb) * F_DIM + f;
  } else {
    const int j = r / (B_DIM * F_DIM);
    const int bb = (r / F_DIM) % B_DIM;
    const int f = r % F_DIM;
    ro = (f * B_DIM + bb) * J_DIM + j;
  }
  const float4 g0 = *(const float4*)&ga[lane * 8];
  const float4 g1 = *(const float4*)&ga[lane * 8 + 4];
  const float4 h0 = *(const float4*)&gb[lane * 8];
  const float4 h1 = *(const float4*)&gb[lane * 8 + 4];
  float y[8];
  y[0] = g0.x * (v[0] - mean) * inv + h0.x;
  y[1] = g0.y * (v[1] - mean) * inv + h0.y;
  y[2] = g0.z * (v[2] - mean) * inv + h0.z;
  y[3] = g0.w * (v[3] - mean) * inv + h0.w;
  y[4] = g1.x * (v[4] - mean) * inv + h1.x;
  y[5] = g1.y * (v[5] - mean) * inv + h1.y;
  y[6] = g1.z * (v[6] - mean) * inv + h1.z;
  y[7] = g1.w * (v[7] - mean) * inv + h1.w;
  if (out) {
    float* orow = out + (size_t)ro * 512 + lane * 8;
    __builtin_nontemporal_store(*(f32x4*)&y[0], (f32x4*)&orow[0]);
    __builtin_nontemporal_store(*(f32x4*)&y[4], (f32x4*)&orow[4]);
  }
  if (outB) {
    us8 o;
#pragma unroll
    for (int e = 0; e < 8; ++e) o[e] = f2b(y[e]);
    __builtin_nontemporal_store(o, (us8*)&outB[(size_t)ro * 512 + lane * 8]);
  }
}

// ---------------------------------------------------------------------------
extern "C" void kernel_launch(void* const* d_in, const int* in_sizes, int n_in,
                              void* d_out, int out_size, void* d_ws, size_t ws_size,
                              hipStream_t stream) {
  const float* x   = (const float*)d_in[0];
  const float* tse = (const float*)d_in[1];
  const float* sWq = (const float*)d_in[5];  const float* sbq = (const float*)d_in[6];
  const float* sWk = (const float*)d_in[7];  const float* sbk = (const float*)d_in[8];
  const float* sWv = (const float*)d_in[9];  const float* sbv = (const float*)d_in[10];
  const float* sWo = (const float*)d_in[11]; const float* sbo = (const float*)d_in[12];
  const float* tWq = (const float*)d_in[13]; const float* tbq = (const float*)d_in[14];
  const float* tWk = (const float*)d_in[15]; const float* tbk = (const float*)d_in[16];
  const float* tWv = (const float*)d_in[17]; const float* tbv = (const float*)d_in[18];
  const float* tWo = (const float*)d_in[19]; const float* tbo = (const float*)d_in[20];
  const float* ffW1 = (const float*)d_in[21]; const float* ffb1 = (const float*)d_in[22];
  const float* ffW2 = (const float*)d_in[23]; const float* ffb2 = (const float*)d_in[24];
  const float* n1a = (const float*)d_in[25]; const float* n1b = (const float*)d_in[26];
  const float* n2a = (const float*)d_in[27]; const float* n2b = (const float*)d_in[28];
  const float* n3a = (const float*)d_in[29]; const float* n3b = (const float*)d_in[30];

  char* p = (char*)d_ws;
  auto carve = [&](size_t bytes) { void* r = (void*)p; p += (bytes + 255) & ~(size_t)255; return r; };

  unsigned short* sQKVt = (unsigned short*)carve((size_t)3 * 512 * 512 * 2);
  unsigned short* sOT   = (unsigned short*)carve((size_t)512 * 512 * 2);
  unsigned short* tQKVt = (unsigned short*)carve((size_t)3 * 512 * 512 * 2);
  unsigned short* tOT   = (unsigned short*)carve((size_t)512 * 512 * 2);
  unsigned short* W1T   = (unsigned short*)carve((size_t)2048 * 512 * 2);
  unsigned short* W2T   = (unsigned short*)carve((size_t)512 * 2048 * 2);
  unsigned short* ktss  = (unsigned short*)carve((size_t)64 * 512 * 2);
  unsigned short* vtss  = (unsigned short*)carve((size_t)64 * 512 * 2);
  unsigned short* ktst  = (unsigned short*)carve((size_t)64 * 512 * 2);
  unsigned short* vtst  = (unsigned short*)carve((size_t)64 * 512 * 2);
  unsigned short* Qb    = (unsigned short*)carve((size_t)M_TOK * 512 * 2);

  unsigned short* Kb = (unsigned short*)d_out;   // K/V bf16 + z1/z2 bf16 alias d_out
  unsigned short* Vb = Kb + (size_t)M_TOK * 512;
  float* outF = (float*)d_out;

  const bool bigws = ws_size >= (size_t)873725952ull;
  float* Rbuf = nullptr;
  unsigned short* Hb  = nullptr;   // [M][2048] bf16 FF hidden; early life: xb | rb1
  unsigned short* xb  = nullptr;
  unsigned short* rb1 = nullptr;
  if (bigws) {
    Hb = (unsigned short*)carve((size_t)M_TOK * 2048 * 2);
    xb = Hb;
    rb1 = Hb + (size_t)M_TOK * 512;
  } else {
    Rbuf = (float*)carve((size_t)M_TOK * 512 * 4);
  }

  const float QSCALE = 0.08838834764831845f; // 1/sqrt(128)

  {
    dim3 tb(32, 8);
    Tc8Args tc;
    tc.W[0] = sWq; tc.WT[0] = sQKVt;
    tc.W[1] = sWk; tc.WT[1] = sQKVt + 262144;
    tc.W[2] = sWv; tc.WT[2] = sQKVt + 524288;
    tc.W[3] = sWo; tc.WT[3] = sOT;
    tc.W[4] = tWq; tc.WT[4] = tQKVt;
    tc.W[5] = tWk; tc.WT[5] = tQKVt + 262144;
    tc.W[6] = tWv; tc.WT[6] = tQKVt + 524288;
    tc.W[7] = tWo; tc.WT[7] = tOT;
    tcast8_k<<<dim3(16, 16, 8), tb, 0, stream>>>(tc);
    tcast_k<<<dim3(64, 16), tb, 0, stream>>>(ffW1, W1T, 512, 2048);
    tcast_k<<<dim3(16, 64), tb, 0, stream>>>(ffW2, W2T, 2048, 512);
  }
  {
    TsArgs ta;
    ta.W[0] = sWk; ta.bias[0] = sbk; ta.out[0] = ktss;
    ta.W[1] = sWv; ta.bias[1] = sbv; ta.out[1] = vtss;
    ta.W[2] = tWk; ta.bias[2] = tbk; ta.out[2] = ktst;
    ta.W[3] = tWv; ta.bias[3] = tbv; ta.out[3] = vtst;
    tsproj_k<<<dim3(B_DIM, 2, 4), 1024, 0, stream>>>(tse, ta);
  }

  const int MT = M_TOK / 128;   // 1320 (fallback grids)
  const int MT2 = M_TOK / 256;  // 660  (256-row tiles; all grids %8==0)

  if (bigws) {
    // ---- spatial attention ----
    cast_k<<<2048, 256, 0, stream>>>(x, xb, M_TOK * 512 / 8);
    gemm256_k<EPI_QKV><<<12 * MT2, 512, 0, stream>>>(
        xb, sQKVt, sbq, sbk, sbv, nullptr, nullptr, Qb, Kb, Vb, 512, 512, 512, 512, 12, QSCALE);
    attn_s_k<<<dim3(F_DIM * B_DIM), 256, 0, stream>>>(Qb, Kb, Vb, ktss, vtss, Qb);
    // z1 = attnO@sWo + sbo + xb -> bf16 into Kb (K dead after attn_s; xb live)
    gemm256_k<EPI_RBB><<<4 * MT2, 512, 0, stream>>>(
        Qb, sOT, sbo, nullptr, nullptr, xb, nullptr, Kb, nullptr, nullptr, 512, 512, 512, 512, 4, 1.f);
    normb_k<<<M_TOK / 4, 256, 0, stream>>>(Kb, nullptr, rb1, n1a, n1b, 1);

    // ---- temporal attention ----
    gemm256_k<EPI_QKV><<<12 * MT2, 512, 0, stream>>>(
        rb1, tQKVt, tbq, tbk, tbv, nullptr, nullptr, Qb, Kb, Vb, 512, 512, 512, 512, 12, QSCALE);
    attn_t_k<<<dim3(J_DIM * B_DIM * H_DIM), 256, 0, stream>>>(Qb, Kb, Vb, ktst, vtst, Qb);
    // z2 = attnO@tWo + tbo + rb1 -> bf16 into Kb (K dead after attn_t)
    gemm256_k<EPI_RBB><<<4 * MT2, 512, 0, stream>>>(
        Qb, tOT, tbo, nullptr, nullptr, rb1, nullptr, Kb, nullptr, nullptr, 512, 512, 512, 512, 4, 1.f);
    normb_k<<<M_TOK / 4, 256, 0, stream>>>(Kb, nullptr, Qb, n2a, n2b, 2);

    // ---- feed-forward: gelu + K=2048 proj; z3 in-place in Qb ----
    gemm256_k<EPI_GELU><<<16 * MT2, 512, 0, stream>>>(
        Qb, W1T, ffb1, nullptr, nullptr, nullptr, nullptr, Hb, nullptr, nullptr,
        512, 512, 2048, 512, 16, 1.f);
    gemm256_k<EPI_RBB><<<4 * MT2, 512, 0, stream>>>(
        Hb, W2T, ffb2, nullptr, nullptr, Qb, nullptr, Qb, nullptr, nullptr,
        2048, 2048, 512, 2048, 4, 1.f);
    normb_k<<<M_TOK / 4, 256, 0, stream>>>(Qb, outF, nullptr, n3a, n3b, 0);
  } else {
    // ---- small-ws fallback (round-6 flow, f32 z-chain) ----
    gemmf_k<EPI_QKV><<<12 * MT, 256, 0, stream>>>(
        x, sQKVt, sbq, sbk, sbv, nullptr, nullptr, Qb, Kb, Vb, 512, 512, 512, 512, 12, QSCALE);
    attn_s_k<<<dim3(F_DIM * B_DIM), 256, 0, stream>>>(Qb, Kb, Vb, ktss, vtss, Qb);
    gemm_k<EPI_RES><<<4 * MT, 256, 0, stream>>>(
        Qb, sOT, sbo, nullptr, nullptr, x, outF, nullptr, nullptr, nullptr, 512, 512, 512, 512, 4, 1.f);
    norm_k<<<M_TOK / 4, 256, 0, stream>>>(outF, Rbuf, nullptr, n1a, n1b, 1);

    gemmf_k<EPI_QKV><<<12 * MT, 256, 0, stream>>>(
        Rbuf, tQKVt, tbq, tbk, tbv, nullptr, nullptr, Qb, Kb, Vb, 512, 512, 512, 512, 12, QSCALE);
    attn_t_k<<<dim3(J_DIM * B_DIM * H_DIM), 256, 0, stream>>>(Qb, Kb, Vb, ktst, vtst, Qb);
    gemm_k<EPI_RES><<<4 * MT, 256, 0, stream>>>(
        Qb, tOT, tbo, nullptr, nullptr, Rbuf, outF, nullptr, nullptr, nullptr, 512, 512, 512, 512, 4, 1.f);
    norm_k<<<M_TOK / 4, 256, 0, stream>>>(outF, Rbuf, Qb, n2a, n2b, 2);

    for (int c = 0; c < 4; ++c) {
      gemm_k<EPI_GELU><<<4 * MT, 256, 0, stream>>>(
          Qb, W1T + (size_t)c * 512 * 512, ffb1 + c * 512, nullptr, nullptr,
          nullptr, nullptr, Qb, nullptr, nullptr, 512, 512, 512, 512, 4, 1.f);
      if (c == 0)
        gemm_k<EPI_RES><<<4 * MT, 256, 0, stream>>>(
            Qb, W2T + c * 512, ffb2, nullptr, nullptr, Rbuf, outF,
            nullptr, nullptr, nullptr, 512, 2048, 512, 512, 4, 1.f);
      else
        gemm_k<EPI_ACC><<<4 * MT, 256, 0, stream>>>(
            Qb, W2T + c * 512, nullptr, nullptr, nullptr, nullptr, outF,
            nullptr, nullptr, nullptr, 512, 2048, 512, 512, 4, 1.f);
    }
    norm_k<<<M_TOK / 4, 256, 0, stream>>>(outF, outF, nullptr, n3a, n3b, 0);
  }
}